// Round 7
// baseline (372.626 us; speedup 1.0000x reference)
//
#include <hip/hip_runtime.h>

typedef short short8 __attribute__((ext_vector_type(8)));
typedef float f32x4 __attribute__((ext_vector_type(4)));
typedef unsigned short ushort;
typedef unsigned int uint;

#define MFMA16(a,b,c) __builtin_amdgcn_mfma_f32_16x16x32_bf16(a,b,c,0,0,0)
#define DPROJ 1552

// ---- workspace byte offsets ----
constexpr size_t OFF_M    = 0;                         // 3*1552 f32
constexpr size_t OFF_CB_B = 0x5000;                    // 1552 f32
constexpr size_t OFF_WT   = 0x8000;                    // 128*512 bf16
constexpr size_t OFF_XT   = 0x30000;                   // [bc128][h16][grp16][p32][e8] u16 = 16 MB
constexpr size_t OFF_DT   = OFF_XT  + 16777216ull;     // 16384*16 f32
constexpr size_t OFF_BCM  = OFF_DT  + 1048576ull;      // [row][512] u16 (B|C)
constexpr size_t OFF_CUM  = OFF_BCM + 16777216ull;     // 2048*128 f32
constexpr size_t OFF_CDC  = OFF_CUM + 1048576ull;      // 2048 f32
constexpr size_t OFF_CBT  = OFF_CDC + 8192ull;         // [bc][grp16][t128][e8] u16 = 4 MB
constexpr size_t OFF_BT   = OFF_CBT + 4194304ull;      // [bc][grp16][n256][e8] u16 = 8 MB
constexpr size_t OFF_ST   = OFF_BT  + 8388608ull;      // YI: [bi][t128][p32] u16 = 16.7 MB
constexpr size_t OFF_Y    = OFF_ST  + 33554432ull;     // 16384*512 bf16

__device__ __forceinline__ float sigm(float x){ return 1.0f/(1.0f + __expf(-x)); }
__device__ __forceinline__ ushort f2bf(float f){
  union { float f; uint u; } c; c.f = f;
  uint u = c.u;
  return (ushort)((u + 0x7FFFu + ((u>>16)&1u)) >> 16);
}
__device__ __forceinline__ float bf2f(ushort h){
  union { uint u; float f; } c; c.u = ((uint)h)<<16;
  return c.f;
}
// XCD swizzle for 2048-block grids: all 16 heads of one (b,c) on one XCD
__device__ __forceinline__ void swz2048(int p, int& bc, int& h){
  int xcd = p & 7, slot = p >> 3;
  bc = xcd*16 + (slot >> 4);
  h  = slot & 15;
}

// ---------------- K0: fuse fc0 into in_proj ----------------
__global__ __launch_bounds__(256) void k0_prep(const float* __restrict__ fc0_w,
                                               const float* __restrict__ fc0_b,
                                               const float* __restrict__ W,
                                               char* __restrict__ wsb){
  float* Mo = (float*)(wsb + OFF_M);
  float* Co = (float*)(wsb + OFF_CB_B);
  int j = blockIdx.x*256 + threadIdx.x;
  if (j >= DPROJ) return;
  float m0=0.f,m1=0.f,m2=0.f,cc=0.f;
  for (int d=0; d<128; ++d){
    float w = W[(size_t)d*DPROJ + j];
    m0 = fmaf(fc0_w[d],     w, m0);
    m1 = fmaf(fc0_w[128+d], w, m1);
    m2 = fmaf(fc0_w[256+d], w, m2);
    cc = fmaf(fc0_b[d],     w, cc);
  }
  Mo[j] = m0; Mo[DPROJ + j] = m1; Mo[2*DPROJ + j] = m2;
  Co[j] = cc;
}

// ---------------- K0b: WoutT'[d][i] = norm_w[i]*Wout[i][d] ----------------------
__global__ __launch_bounds__(256) void k0b_wt(const float* __restrict__ norm_w,
                                              const float* __restrict__ Wout,
                                              char* __restrict__ wsb){
  ushort* WT = (ushort*)(wsb + OFF_WT);
  int d = blockIdx.x;
  for (int i = threadIdx.x; i < 512; i += 256)
    WT[(size_t)d*512 + i] = f2bf(norm_w[i]*Wout[(size_t)i*128 + d]);
}

// ------ K12: fused proj+causal conv(4)+silu -> xT tiled / BC row / BT tiled -----
__device__ __forceinline__ void proj8(int li, const float* __restrict__ xb,
                                      const float* m0, const float* m1, const float* m2,
                                      const float* c8, float* dst){
  if (li < 0){
    #pragma unroll
    for (int j=0;j<8;++j) dst[j] = 0.f;
    return;
  }
  int hh, wv;
  if (li < 4096){ hh = li>>6; wv = li&63; }
  else { int l2 = li-4096; hh = 63-(l2>>6); wv = 63-(l2&63); }
  float x0 = xb[hh*64+wv], x1 = xb[4096+hh*64+wv], x2 = xb[8192+hh*64+wv];
  #pragma unroll
  for (int j=0;j<8;++j)
    dst[j] = fmaf(x2, m2[j], fmaf(x1, m1[j], fmaf(x0, m0[j], c8[j])));
}

__device__ __forceinline__ void conv8(const float* cb8, const float* cw0, const float* cw1,
                                      const float* cw2, const float* cw3,
                                      const float* wA, const float* wB,
                                      const float* wC, const float* wD, ushort* o){
  #pragma unroll
  for (int j=0;j<8;++j){
    float a = cb8[j];
    a = fmaf(wA[j], cw0[j], a);
    a = fmaf(wB[j], cw1[j], a);
    a = fmaf(wC[j], cw2[j], a);
    a = fmaf(wD[j], cw3[j], a);
    o[j] = f2bf(a * sigm(a));
  }
}

__global__ __launch_bounds__(256) void k12_projconv(const float* __restrict__ x,
                                                    const float* __restrict__ conv_w,
                                                    const float* __restrict__ conv_b,
                                                    char* __restrict__ wsb){
  int tid = threadIdx.x;
  int cg = tid & 127, rl = tid >> 7;
  int row0 = blockIdx.x*16 + rl*8;        // 1024 blocks, 16 rows each
  int b = row0 >> 13, l0 = row0 & 8191;
  const float* M  = (const float*)(wsb + OFF_M);
  const float* Cc = (const float*)(wsb + OFF_CB_B);
  const float* xb = x + (size_t)b*12288;
  int ch0 = cg*8, j0 = 512 + ch0;
  float m0[8],m1[8],m2[8],c8[8],cw0[8],cw1[8],cw2[8],cw3[8],cb8[8];
  #pragma unroll
  for (int j=0;j<8;++j){
    m0[j]=M[j0+j]; m1[j]=M[DPROJ+j0+j]; m2[j]=M[2*DPROJ+j0+j]; c8[j]=Cc[j0+j];
    cw0[j]=conv_w[(ch0+j)*4+0]; cw1[j]=conv_w[(ch0+j)*4+1];
    cw2[j]=conv_w[(ch0+j)*4+2]; cw3[j]=conv_w[(ch0+j)*4+3];
    cb8[j]=conv_b[ch0+j];
  }
  bool is_xs = (ch0 < 512);
  bool is_b  = (ch0 >= 512) && (ch0 < 768);
  bool pack  = is_xs || is_b;
  ushort* bcmp = (ushort*)(wsb + OFF_BCM);
  int chb = ch0 - 512;
  uint colw[8][4];        // [ch j][row-pair] packed bf16x2, static idx only
  ushort oprev[8];
  float w0[8],w1[8],w2[8],w3[8];
  ushort o[8];
  proj8(l0-3, xb, m0,m1,m2,c8, w1);
  proj8(l0-2, xb, m0,m1,m2,c8, w2);
  proj8(l0-1, xb, m0,m1,m2,c8, w3);

#define ROW_EVEN(R, WN, WA, WB, WC)                                          \
  proj8(l0+R, xb, m0,m1,m2,c8, WN);                                          \
  conv8(cb8,cw0,cw1,cw2,cw3, WA,WB,WC,WN, o);                                \
  if (pack){ _Pragma("unroll")                                               \
    for (int j=0;j<8;++j) oprev[j] = o[j]; }                                 \
  if (!is_xs) *(uint4*)(bcmp + (size_t)(row0+R)*512 + chb) = *(uint4*)o;
#define ROW_ODD(R, WN, WA, WB, WC)                                           \
  proj8(l0+R, xb, m0,m1,m2,c8, WN);                                          \
  conv8(cb8,cw0,cw1,cw2,cw3, WA,WB,WC,WN, o);                                \
  if (pack){ _Pragma("unroll")                                               \
    for (int j=0;j<8;++j) colw[j][(R)>>1] = (uint)oprev[j] | ((uint)o[j]<<16); } \
  if (!is_xs) *(uint4*)(bcmp + (size_t)(row0+R)*512 + chb) = *(uint4*)o;

  ROW_EVEN(0, w0, w1,w2,w3)
  ROW_ODD (1, w1, w2,w3,w0)
  ROW_EVEN(2, w2, w3,w0,w1)
  ROW_ODD (3, w3, w0,w1,w2)
  ROW_EVEN(4, w0, w1,w2,w3)
  ROW_ODD (5, w1, w2,w3,w0)
  ROW_EVEN(6, w2, w3,w0,w1)
  ROW_ODD (7, w3, w0,w1,w2)
#undef ROW_EVEN
#undef ROW_ODD

  int bc = row0>>7, grp = (row0&127)>>3;
  if (is_xs){
    int h = ch0>>5, p0 = ch0&31;
    ushort* dst = (ushort*)(wsb+OFF_XT) + (((size_t)(bc*16+h)*16 + grp)*32)*8;
    #pragma unroll
    for (int j=0;j<8;++j){
      uint4 v; v.x = colw[j][0]; v.y = colw[j][1]; v.z = colw[j][2]; v.w = colw[j][3];
      *(uint4*)(dst + (size_t)(p0+j)*8) = v;
    }
  } else if (is_b){
    // BT tiled: [bc][grp16][n256][e8]; e = row index within grp, n = chb+j
    ushort* btb = (ushort*)(wsb+OFF_BT) + (size_t)bc*32768;
    #pragma unroll
    for (int j=0;j<8;++j){
      uint4 v; v.x = colw[j][0]; v.y = colw[j][1]; v.z = colw[j][2]; v.w = colw[j][3];
      *(uint4*)(btb + (size_t)(grp*256 + chb + j)*8) = v;
    }
  }
}

// ------- K3: dt = softplus(proj+bias) fused + per (b,c,h) cumsum of dt*A --------
__global__ __launch_bounds__(128) void k3_cum(const float* __restrict__ x,
                                              const float* __restrict__ dt_bias,
                                              const float* __restrict__ A_log,
                                              char* __restrict__ wsb){
  int bi = blockIdx.x;                    // (b*64+c)*16 + h
  int h = bi & 15; int bc = bi >> 4;
  int t = threadIdx.x;
  int r = bc*128 + t;
  int b = r >> 13, l = r & 8191;
  int hp, wv;
  if (l < 4096){ hp = l>>6; wv = l&63; }
  else { int l2 = l-4096; hp = 63-(l2>>6); wv = 63-(l2&63); }
  const float* xb = x + (size_t)b*12288;
  float x0 = xb[hp*64+wv], x1 = xb[4096+hp*64+wv], x2 = xb[8192+hp*64+wv];
  const float* M  = (const float*)(wsb + OFF_M);
  const float* Cc = (const float*)(wsb + OFF_CB_B);
  int j = 1536 + h;
  float v = Cc[j];
  v = fmaf(x0, M[j], v);
  v = fmaf(x1, M[DPROJ+j], v);
  v = fmaf(x2, M[2*DPROJ+j], v);
  float tt = v + dt_bias[h];
  float dtv = (tt > 20.f) ? tt : log1pf(__expf(tt));
  ((float*)(wsb+OFF_DT))[(size_t)r*16 + h] = dtv;
  __shared__ float s[128];
  float A = -__expf(A_log[h]);
  s[t] = dtv * A; __syncthreads();
  for (int off=1; off<128; off<<=1){
    float sv = (t>=off) ? s[t-off] : 0.f;
    __syncthreads();
    s[t] += sv;
    __syncthreads();
  }
  ((float*)(wsb + OFF_CUM))[(size_t)bi*128 + t] = s[t];
  if (t==127) ((float*)(wsb + OFF_CDC))[bi] = __expf(s[127]);
}

// ------- K4a: CB = C·B^T via MFMA -> cbt tiled [grp][t][e] ----------------------
__global__ __launch_bounds__(256) void k4a_cb(char* __restrict__ wsb){
  int bi = blockIdx.x;                    // (b*64+c)*4 + squad
  int sq = bi & 3; int bc = bi >> 2;
  __shared__ __align__(16) char sC[16384];   // C[128][64] bf16 swizzled rows(128B)
  __shared__ __align__(16) char sB[4096];    // B[32][64]  bf16 swizzled
  const ushort* bcm = (const ushort*)(wsb + OFF_BCM);
  ushort* cbtT = (ushort*)(wsb + OFF_CBT) + (size_t)bc*16384;
  size_t rb = (size_t)bc*128;
  int tid = threadIdx.x;
  int lane = tid&63, wid = tid>>6, l15 = lane&15, l4 = lane>>4;
  int s_base = sq*32;
  f32x4 acc[2][2] = {};
  for (int nt = 0; nt < 4; ++nt){
    int n0 = nt*64;
    __syncthreads();
    for (int idx = tid; idx < 1024; idx += 256){
      int t = idx>>3, c = idx&7;
      uint4 v = *(const uint4*)(bcm + (rb+t)*512 + 256 + n0 + c*8);
      *(uint4*)(sC + ((t*128 + c*16) ^ ((t&7)<<4))) = v;
    }
    {
      int idx = tid;
      int s = idx>>3, c = idx&7;
      uint4 v = *(const uint4*)(bcm + (rb+s_base+s)*512 + n0 + c*8);
      *(uint4*)(sB + ((s*128 + c*16) ^ ((s&7)<<4))) = v;
    }
    __syncthreads();
    #pragma unroll
    for (int ks = 0; ks < 2; ++ks){
      int kb = ks*64 + l4*16;
      int t0 = wid*32 + l15, t1 = t0 + 16;
      short8 a0 = *(const short8*)(sC + ((t0*128 + kb) ^ ((t0&7)<<4)));
      short8 a1 = *(const short8*)(sC + ((t1*128 + kb) ^ ((t1&7)<<4)));
      short8 b0 = *(const short8*)(sB + ((l15*128 + kb) ^ ((l15&7)<<4)));
      short8 b1 = *(const short8*)(sB + (((16+l15)*128 + kb) ^ (((16+l15)&7)<<4)));
      acc[0][0] = MFMA16(a0,b0,acc[0][0]);
      acc[0][1] = MFMA16(a0,b1,acc[0][1]);
      acc[1][0] = MFMA16(a1,b0,acc[1][0]);
      acc[1][1] = MFMA16(a1,b1,acc[1][1]);
    }
  }
  #pragma unroll
  for (int mt=0; mt<2; ++mt)
  #pragma unroll
  for (int st=0; st<2; ++st)
  #pragma unroll
  for (int r=0; r<4; ++r){
    int t = wid*32 + mt*16 + l4*4 + r;
    int s = s_base + st*16 + l15;
    cbtT[(size_t)((s>>3)*128 + t)*8 + (s&7)] = f2bf(acc[mt][st][r]);
  }
}

// ------- KSCAN: persistent chunk scan: y_inter -> YI, S update (64 blocks) ------
// block = b*32 + h*2 + ph; 512 threads (8 waves). S[16 p][256 n] lives in LDS.
__global__ __launch_bounds__(512) void kscan(char* __restrict__ wsb){
  int blk = blockIdx.x;
  int ph = blk & 1, h = (blk>>1)&15, b = blk>>5;
  __shared__ float sS[4096];                  // S f32 [16][256]
  __shared__ __align__(16) char sSb[8192];    // S bf16 [16][256], XOR-swizzled rows 512B
  __shared__ float sW[128], sE[128];
  const ushort* xtb = (const ushort*)(wsb + OFF_XT);
  const ushort* btb0= (const ushort*)(wsb + OFF_BT);
  const ushort* bcm = (const ushort*)(wsb + OFF_BCM);
  const float* cumb = (const float*)(wsb + OFF_CUM);
  const float* dtp  = (const float*)(wsb + OFF_DT);
  const float* cdcp = (const float*)(wsb + OFF_CDC);
  ushort* YI = (ushort*)(wsb + OFF_ST);
  int tid = threadIdx.x;
  int lane = tid&63, wave = tid>>6, l15 = lane&15, l4 = lane>>4;
  for (int i = tid; i < 4096; i += 512) sS[i] = 0.f;
  for (int i = tid; i < 4096; i += 512) ((ushort*)sSb)[i] = 0;
  __syncthreads();
  for (int c = 0; c < 64; ++c){
    int bcc = b*64 + c;
    int bi = bcc*16 + h;
    size_t rb = (size_t)bcc*128;
    if (tid < 128){
      float cv = cumb[(size_t)bi*128 + tid];
      float c127 = cumb[(size_t)bi*128 + 127];
      sW[tid] = __expf(c127 - cv) * dtp[(rb+tid)*16 + h];
      sE[tid] = __expf(cv);
    }
    __syncthreads();
    // ---- y_inter = C @ S^T (S BEFORE update): wave owns t-range wave*16 ----
    const ushort* xt  = xtb + (size_t)bi*4096;
    const ushort* btb = btb0 + (size_t)bcc*32768;
    f32x4 accY = {};
    #pragma unroll
    for (int ks = 0; ks < 8; ++ks){
      short8 a = *(const short8*)(bcm + (rb + wave*16 + l15)*512 + 256 + ks*32 + l4*8);
      short8 bS = *(const short8*)(sSb + ((l15*512 + ks*64 + l4*16) ^ ((l15&7)<<4)));
      accY = MFMA16(a, bS, accY);
    }
    // ---- states = (x*w)^T @ B: M=p(16, this ph), N=n(32 per wave), K=s(128) ----
    f32x4 accS[2] = {};
    #pragma unroll
    for (int ks = 0; ks < 4; ++ks){
      int grp = ks*4 + l4;
      const float* wp = sW + grp*8;
      short8 rx = *(const short8*)(xt + (size_t)(grp*32 + ph*16 + l15)*8);
      short8 ax;
      #pragma unroll
      for (int j=0;j<8;++j) ax[j] = (short)f2bf(bf2f((ushort)rx[j]) * wp[j]);
      #pragma unroll
      for (int nt2 = 0; nt2 < 2; ++nt2){
        int n = wave*32 + nt2*16 + l15;
        short8 bB = *(const short8*)(btb + (size_t)(grp*256 + n)*8);
        accS[nt2] = MFMA16(ax, bB, accS[nt2]);
      }
    }
    // ---- write YI (scaled by exp(cum[t])) ----
    #pragma unroll
    for (int r = 0; r < 4; ++r){
      int t = wave*16 + l4*4 + r;
      YI[(size_t)bi*4096 + t*32 + ph*16 + l15] = f2bf(accY[r] * sE[t]);
    }
    // ---- S = S*cd + states (each element owned by exactly one lane) ----
    float cd = cdcp[bi];
    #pragma unroll
    for (int nt2 = 0; nt2 < 2; ++nt2)
    #pragma unroll
    for (int r = 0; r < 4; ++r){
      int p = l4*4 + r;
      int n = wave*32 + nt2*16 + l15;
      int a = p*256 + n;
      sS[a] = fmaf(sS[a], cd, accS[nt2][r]);
    }
    __syncthreads();
    // ---- convert S -> bf16 swizzled ----
    {
      int i0 = tid*8;
      int p = i0 >> 8, n = i0 & 255;
      ushort o[8];
      #pragma unroll
      for (int j=0;j<8;++j) o[j] = f2bf(sS[i0+j]);
      *(uint4*)(sSb + ((p*512 + n*2) ^ ((p&7)<<4))) = *(uint4*)o;
    }
    __syncthreads();
  }
}

// -------- K4y: y = attn@x + YI + D*x -> Y bf16 ----------------------------------
__global__ __launch_bounds__(256) void k4y_out(const float* __restrict__ Dp,
                                               char* __restrict__ wsb){
  int bc, h; swz2048(blockIdx.x, bc, h);
  int bi = bc*16 + h;
  __shared__ float sCum[128], sDt[128];
  const ushort* cbt = (const ushort*)(wsb + OFF_CBT) + (size_t)bc*16384;
  const ushort* xt  = (const ushort*)(wsb + OFF_XT) + (size_t)bi*4096;
  const ushort* YIp = (const ushort*)(wsb + OFF_ST) + (size_t)bi*4096;
  const float* cum  = (const float*)(wsb + OFF_CUM) + (size_t)bi*128;
  const float* dtp  = (const float*)(wsb + OFF_DT);
  ushort* Yb = (ushort*)(wsb + OFF_Y);
  size_t rb = (size_t)bc*128;
  int tid = threadIdx.x;
  if (tid < 128){
    sCum[tid] = cum[tid];
    sDt[tid]  = dtp[(rb+tid)*16 + h];
  }
  __syncthreads();
  int lane = tid&63, wid = tid>>6, l15 = lane&15, l4 = lane>>4;
  int t0 = wid*32 + l15, t1 = t0 + 16;
  float ct0 = sCum[t0], ct1 = sCum[t1];
  // ---- y_intra: A = CB*decay*dt built in-register, B = xT frags ----
  f32x4 acc[2][2] = {};
  #pragma unroll
  for (int ks = 0; ks < 4; ++ks){
    int grp = ks*4 + l4;
    int s0 = grp*8;
    short8 ra0 = *(const short8*)(cbt + (size_t)(grp*128 + t0)*8);
    short8 ra1 = *(const short8*)(cbt + (size_t)(grp*128 + t1)*8);
    short8 a0, a1;
    #pragma unroll
    for (int j=0;j<8;++j){
      int s = s0 + j;
      float cs = sCum[s], ds = sDt[s];
      float e0 = __expf(fminf(ct0 - cs, 0.f)) * ds;
      float e1 = __expf(fminf(ct1 - cs, 0.f)) * ds;
      float v0 = (t0 >= s) ? bf2f((ushort)ra0[j]) * e0 : 0.f;
      float v1 = (t1 >= s) ? bf2f((ushort)ra1[j]) * e1 : 0.f;
      a0[j] = (short)f2bf(v0);
      a1[j] = (short)f2bf(v1);
    }
    short8 b0 = *(const short8*)(xt + (size_t)(grp*32 + l15)*8);
    short8 b1 = *(const short8*)(xt + (size_t)(grp*32 + 16 + l15)*8);
    acc[0][0] = MFMA16(a0,b0,acc[0][0]);
    acc[0][1] = MFMA16(a0,b1,acc[0][1]);
    acc[1][0] = MFMA16(a1,b0,acc[1][0]);
    acc[1][1] = MFMA16(a1,b1,acc[1][1]);
  }
  float Dh = Dp[h];
  #pragma unroll
  for (int mt=0; mt<2; ++mt){
    int tb = wid*32 + mt*16 + l4*4;
    int tg = tb>>3, e0 = tb&7;
    #pragma unroll
    for (int nt=0; nt<2; ++nt){
      int p = nt*16 + l15;
      ushort xv[4];
      *(uint2*)xv = *(const uint2*)(xt + (size_t)(tg*32 + p)*8 + e0);
      #pragma unroll
      for (int r=0; r<4; ++r){
        int t = tb + r;
        float yi = bf2f(YIp[t*32 + p]);
        float yv = acc[mt][nt][r] + yi + Dh*bf2f(xv[r]);
        Yb[(rb+t)*512 + h*32 + p] = f2bf(yv);
      }
    }
  }
}

// ---------------- K7: gate(silu(z)) -> RMS -> out_proj (MFMA) -------------------
__global__ __launch_bounds__(256) void k7_final(const float* __restrict__ x,
                                                char* __restrict__ wsb,
                                                float* __restrict__ out){
  int r0 = blockIdx.x*32;                  // 512 blocks
  __shared__ __align__(16) char sG[32768]; // G[32][512] bf16 rows 1024B, swizzled
  __shared__ float sScale[32];
  const ushort* Yb = (const ushort*)(wsb + OFF_Y);
  const float* M  = (const float*)(wsb + OFF_M);
  const float* Cb = (const float*)(wsb + OFF_CB_B);
  const ushort* WT = (const ushort*)(wsb + OFF_WT);
  int tid = threadIdx.x;
  int r = tid>>3, li = tid&7;
  int row = r0 + r; int b = row>>13, l = row & 8191;
  int hh, wv;
  if (l < 4096){ hh = l>>6; wv = l&63; }
  else { int l2 = l-4096; hh = 63-(l2>>6); wv = 63-(l2&63); }
  const float* xb = x + (size_t)b*12288;
  float x0 = xb[hh*64+wv], x1 = xb[4096+hh*64+wv], x2 = xb[8192+hh*64+wv];
  float sq = 0.f;
  #pragma unroll
  for (int k = 0; k < 8; ++k){
    int i0 = li*64 + k*8;
    short8 yv = *(const short8*)(Yb + (size_t)row*512 + i0);
    ushort g8[8];
    #pragma unroll
    for (int j=0;j<8;++j){
      int i = i0 + j;
      float z = Cb[i];
      z = fmaf(x0, M[i], z);
      z = fmaf(x1, M[DPROJ+i], z);
      z = fmaf(x2, M[2*DPROJ+i], z);
      float g = bf2f((ushort)yv[j]) * z * sigm(z);
      sq = fmaf(g, g, sq);
      g8[j] = f2bf(g);
    }
    *(uint4*)(sG + ((r*1024 + i0*2) ^ ((r&7)<<4))) = *(uint4*)g8;
  }
  sq += __shfl_xor(sq, 1, 64);
  sq += __shfl_xor(sq, 2, 64);
  sq += __shfl_xor(sq, 4, 64);
  if (li == 0) sScale[r] = rsqrtf(sq*(1.f/512.f) + 1e-5f);
  __syncthreads();
  int lane = tid&63, wid = tid>>6, l15 = lane&15, l4 = lane>>4;
  f32x4 acc[2][2] = {};
  #pragma unroll
  for (int ks = 0; ks < 16; ++ks){
    int kb = ks*64 + l4*16;
    int rr0 = l15, rr1 = 16+l15;
    short8 a0 = *(const short8*)(sG + ((rr0*1024 + kb) ^ ((rr0&7)<<4)));
    short8 a1 = *(const short8*)(sG + ((rr1*1024 + kb) ^ ((rr1&7)<<4)));
    int koff = ks*32 + l4*8;
    short8 b0 = *(const short8*)(WT + (size_t)(wid*32 + l15)*512 + koff);
    short8 b1 = *(const short8*)(WT + (size_t)(wid*32 + 16 + l15)*512 + koff);
    acc[0][0] = MFMA16(a0,b0,acc[0][0]);
    acc[0][1] = MFMA16(a0,b1,acc[0][1]);
    acc[1][0] = MFMA16(a1,b0,acc[1][0]);
    acc[1][1] = MFMA16(a1,b1,acc[1][1]);
  }
  #pragma unroll
  for (int mt=0; mt<2; ++mt)
  #pragma unroll
  for (int nt=0; nt<2; ++nt)
  #pragma unroll
  for (int r4=0; r4<4; ++r4){
    int rr = mt*16 + l4*4 + r4;
    int d = wid*32 + nt*16 + l15;
    out[(size_t)(r0+rr)*128 + d] = acc[mt][nt][r4] * sScale[rr];
  }
}

extern "C" void kernel_launch(void* const* d_in, const int* in_sizes, int n_in,
                              void* d_out, int out_size, void* d_ws, size_t ws_size,
                              hipStream_t stream) {
  const float* x         = (const float*)d_in[0];
  const float* fc0_w     = (const float*)d_in[1];
  const float* fc0_b     = (const float*)d_in[2];
  const float* in_proj_w = (const float*)d_in[3];
  const float* conv_w    = (const float*)d_in[4];
  const float* conv_b    = (const float*)d_in[5];
  const float* dt_bias   = (const float*)d_in[6];
  const float* A_log     = (const float*)d_in[7];
  const float* Dp        = (const float*)d_in[8];
  const float* norm_w    = (const float*)d_in[9];
  const float* out_proj_w= (const float*)d_in[10];
  char* wsb  = (char*)d_ws;
  float* out = (float*)d_out;

  k0_prep<<<dim3(7),     dim3(256), 0, stream>>>(fc0_w, fc0_b, in_proj_w, wsb);
  k0b_wt <<<dim3(128),   dim3(256), 0, stream>>>(norm_w, out_proj_w, wsb);
  k12_projconv<<<dim3(1024), dim3(256), 0, stream>>>(x, conv_w, conv_b, wsb);
  k3_cum <<<dim3(2048),  dim3(128), 0, stream>>>(x, dt_bias, A_log, wsb);
  kscan  <<<dim3(64),    dim3(512), 0, stream>>>(wsb);
  k4a_cb <<<dim3(512),   dim3(256), 0, stream>>>(wsb);
  k4y_out<<<dim3(2048),  dim3(256), 0, stream>>>(Dp, wsb);
  k7_final<<<dim3(512),  dim3(256), 0, stream>>>(x, wsb, out);
}

// Round 8
// 153.660 us; speedup vs baseline: 2.4250x; 2.4250x over previous
//
#include <hip/hip_runtime.h>

typedef short short8 __attribute__((ext_vector_type(8)));
typedef float f32x4 __attribute__((ext_vector_type(4)));
typedef unsigned short ushort;
typedef unsigned int uint;

#define MFMA16(a,b,c) __builtin_amdgcn_mfma_f32_16x16x32_bf16(a,b,c,0,0,0)
#define DPROJ 1552
#define LOG2E 1.44269504f

// ---- workspace byte offsets ----
constexpr size_t OFF_M    = 0;                         // 3*1552 f32
constexpr size_t OFF_CB_B = 0x5000;                    // 1552 f32
constexpr size_t OFF_WT   = 0x8000;                    // 128*512 bf16
constexpr size_t OFF_XT   = 0x30000;                   // [bc128][h16][grp16][p32][e8] u16 = 16 MB
constexpr size_t OFF_DT   = OFF_XT  + 16777216ull;     // 16384*16 f32
constexpr size_t OFF_BCM  = OFF_DT  + 1048576ull;      // [row][512] u16 (B|C)
constexpr size_t OFF_CUM  = OFF_BCM + 16777216ull;     // 2048*128 f32 (log2 units)
constexpr size_t OFF_CDC  = OFF_CUM + 1048576ull;      // 2048 f32
constexpr size_t OFF_CBT  = OFF_CDC + 8192ull;         // [bc][grp16][t128][e8] u16 = 4 MB
constexpr size_t OFF_BT   = OFF_CBT + 4194304ull;      // [bc][grp16][n256][e8] u16 = 8 MB
constexpr size_t OFF_ST   = OFF_BT  + 8388608ull;      // [bi][grp32][p32][e8] u16 = 32 MB
constexpr size_t OFF_Y    = OFF_ST  + 33554432ull;     // 16384*512 bf16

__device__ __forceinline__ float sigm(float x){ return 1.0f/(1.0f + __expf(-x)); }
__device__ __forceinline__ ushort f2bf(float f){
  union { float f; uint u; } c; c.f = f;
  uint u = c.u;
  return (ushort)((u + 0x7FFFu + ((u>>16)&1u)) >> 16);
}
__device__ __forceinline__ float bf2f(ushort h){
  union { uint u; float f; } c; c.u = ((uint)h)<<16;
  return c.f;
}
// XCD swizzle for 2048-block grids: all 16 heads of one (b,c) on one XCD
__device__ __forceinline__ void swz2048(int p, int& bc, int& h){
  int xcd = p & 7, slot = p >> 3;
  bc = xcd*16 + (slot >> 4);
  h  = slot & 15;
}

// ---------------- K0: fuse fc0 into in_proj ----------------
__global__ __launch_bounds__(256) void k0_prep(const float* __restrict__ fc0_w,
                                               const float* __restrict__ fc0_b,
                                               const float* __restrict__ W,
                                               char* __restrict__ wsb){
  float* Mo = (float*)(wsb + OFF_M);
  float* Co = (float*)(wsb + OFF_CB_B);
  int j = blockIdx.x*256 + threadIdx.x;
  if (j >= DPROJ) return;
  float m0=0.f,m1=0.f,m2=0.f,cc=0.f;
  for (int d=0; d<128; ++d){
    float w = W[(size_t)d*DPROJ + j];
    m0 = fmaf(fc0_w[d],     w, m0);
    m1 = fmaf(fc0_w[128+d], w, m1);
    m2 = fmaf(fc0_w[256+d], w, m2);
    cc = fmaf(fc0_b[d],     w, cc);
  }
  Mo[j] = m0; Mo[DPROJ + j] = m1; Mo[2*DPROJ + j] = m2;
  Co[j] = cc;
}

// ---------------- K0b: WoutT'[d][i] = norm_w[i]*Wout[i][d] ----------------------
__global__ __launch_bounds__(256) void k0b_wt(const float* __restrict__ norm_w,
                                              const float* __restrict__ Wout,
                                              char* __restrict__ wsb){
  ushort* WT = (ushort*)(wsb + OFF_WT);
  int d = blockIdx.x;
  for (int i = threadIdx.x; i < 512; i += 256)
    WT[(size_t)d*512 + i] = f2bf(norm_w[i]*Wout[(size_t)i*128 + d]);
}

// ------ K12: fused proj+causal conv(4)+silu -> xT tiled / BC row / BT tiled -----
__device__ __forceinline__ void proj8(int li, const float* __restrict__ xb,
                                      const float* m0, const float* m1, const float* m2,
                                      const float* c8, float* dst){
  if (li < 0){
    #pragma unroll
    for (int j=0;j<8;++j) dst[j] = 0.f;
    return;
  }
  int hh, wv;
  if (li < 4096){ hh = li>>6; wv = li&63; }
  else { int l2 = li-4096; hh = 63-(l2>>6); wv = 63-(l2&63); }
  float x0 = xb[hh*64+wv], x1 = xb[4096+hh*64+wv], x2 = xb[8192+hh*64+wv];
  #pragma unroll
  for (int j=0;j<8;++j)
    dst[j] = fmaf(x2, m2[j], fmaf(x1, m1[j], fmaf(x0, m0[j], c8[j])));
}

__device__ __forceinline__ void conv8(const float* cb8, const float* cw0, const float* cw1,
                                      const float* cw2, const float* cw3,
                                      const float* wA, const float* wB,
                                      const float* wC, const float* wD, ushort* o){
  #pragma unroll
  for (int j=0;j<8;++j){
    float a = cb8[j];
    a = fmaf(wA[j], cw0[j], a);
    a = fmaf(wB[j], cw1[j], a);
    a = fmaf(wC[j], cw2[j], a);
    a = fmaf(wD[j], cw3[j], a);
    o[j] = f2bf(a * sigm(a));
  }
}

__global__ __launch_bounds__(256) void k12_projconv(const float* __restrict__ x,
                                                    const float* __restrict__ conv_w,
                                                    const float* __restrict__ conv_b,
                                                    char* __restrict__ wsb){
  int tid = threadIdx.x;
  int cg = tid & 127, rl = tid >> 7;
  int row0 = blockIdx.x*16 + rl*8;        // 1024 blocks, 16 rows each
  int b = row0 >> 13, l0 = row0 & 8191;
  const float* M  = (const float*)(wsb + OFF_M);
  const float* Cc = (const float*)(wsb + OFF_CB_B);
  const float* xb = x + (size_t)b*12288;
  int ch0 = cg*8, j0 = 512 + ch0;
  float m0[8],m1[8],m2[8],c8[8],cw0[8],cw1[8],cw2[8],cw3[8],cb8[8];
  #pragma unroll
  for (int j=0;j<8;++j){
    m0[j]=M[j0+j]; m1[j]=M[DPROJ+j0+j]; m2[j]=M[2*DPROJ+j0+j]; c8[j]=Cc[j0+j];
    cw0[j]=conv_w[(ch0+j)*4+0]; cw1[j]=conv_w[(ch0+j)*4+1];
    cw2[j]=conv_w[(ch0+j)*4+2]; cw3[j]=conv_w[(ch0+j)*4+3];
    cb8[j]=conv_b[ch0+j];
  }
  bool is_xs = (ch0 < 512);
  bool is_b  = (ch0 >= 512) && (ch0 < 768);
  bool pack  = is_xs || is_b;
  ushort* bcmp = (ushort*)(wsb + OFF_BCM);
  int chb = ch0 - 512;
  uint colw[8][4];        // [ch j][row-pair] packed bf16x2, static idx only
  ushort oprev[8];
  float w0[8],w1[8],w2[8],w3[8];
  ushort o[8];
  proj8(l0-3, xb, m0,m1,m2,c8, w1);
  proj8(l0-2, xb, m0,m1,m2,c8, w2);
  proj8(l0-1, xb, m0,m1,m2,c8, w3);

#define ROW_EVEN(R, WN, WA, WB, WC)                                          \
  proj8(l0+R, xb, m0,m1,m2,c8, WN);                                          \
  conv8(cb8,cw0,cw1,cw2,cw3, WA,WB,WC,WN, o);                                \
  if (pack){ _Pragma("unroll")                                               \
    for (int j=0;j<8;++j) oprev[j] = o[j]; }                                 \
  if (!is_xs) *(uint4*)(bcmp + (size_t)(row0+R)*512 + chb) = *(uint4*)o;
#define ROW_ODD(R, WN, WA, WB, WC)                                           \
  proj8(l0+R, xb, m0,m1,m2,c8, WN);                                          \
  conv8(cb8,cw0,cw1,cw2,cw3, WA,WB,WC,WN, o);                                \
  if (pack){ _Pragma("unroll")                                               \
    for (int j=0;j<8;++j) colw[j][(R)>>1] = (uint)oprev[j] | ((uint)o[j]<<16); } \
  if (!is_xs) *(uint4*)(bcmp + (size_t)(row0+R)*512 + chb) = *(uint4*)o;

  ROW_EVEN(0, w0, w1,w2,w3)
  ROW_ODD (1, w1, w2,w3,w0)
  ROW_EVEN(2, w2, w3,w0,w1)
  ROW_ODD (3, w3, w0,w1,w2)
  ROW_EVEN(4, w0, w1,w2,w3)
  ROW_ODD (5, w1, w2,w3,w0)
  ROW_EVEN(6, w2, w3,w0,w1)
  ROW_ODD (7, w3, w0,w1,w2)
#undef ROW_EVEN
#undef ROW_ODD

  int bc = row0>>7, grp = (row0&127)>>3;
  if (is_xs){
    int h = ch0>>5, p0 = ch0&31;
    ushort* dst = (ushort*)(wsb+OFF_XT) + (((size_t)(bc*16+h)*16 + grp)*32)*8;
    #pragma unroll
    for (int j=0;j<8;++j){
      uint4 v; v.x = colw[j][0]; v.y = colw[j][1]; v.z = colw[j][2]; v.w = colw[j][3];
      *(uint4*)(dst + (size_t)(p0+j)*8) = v;
    }
  } else if (is_b){
    // BT tiled: [bc][grp16][n256][e8]
    ushort* btb = (ushort*)(wsb+OFF_BT) + (size_t)bc*32768;
    #pragma unroll
    for (int j=0;j<8;++j){
      uint4 v; v.x = colw[j][0]; v.y = colw[j][1]; v.z = colw[j][2]; v.w = colw[j][3];
      *(uint4*)(btb + (size_t)(grp*256 + chb + j)*8) = v;
    }
  }
}

// ------- K3: dt = softplus(proj+bias) fused + per (b,c,h) cumsum of dt*A*log2e --
__global__ __launch_bounds__(128) void k3_cum(const float* __restrict__ x,
                                              const float* __restrict__ dt_bias,
                                              const float* __restrict__ A_log,
                                              char* __restrict__ wsb){
  int bi = blockIdx.x;                    // (b*64+c)*16 + h
  int h = bi & 15; int bc = bi >> 4;
  int t = threadIdx.x;
  int r = bc*128 + t;
  int b = r >> 13, l = r & 8191;
  int hp, wv;
  if (l < 4096){ hp = l>>6; wv = l&63; }
  else { int l2 = l-4096; hp = 63-(l2>>6); wv = 63-(l2&63); }
  const float* xb = x + (size_t)b*12288;
  float x0 = xb[hp*64+wv], x1 = xb[4096+hp*64+wv], x2 = xb[8192+hp*64+wv];
  const float* M  = (const float*)(wsb + OFF_M);
  const float* Cc = (const float*)(wsb + OFF_CB_B);
  int j = 1536 + h;
  float v = Cc[j];
  v = fmaf(x0, M[j], v);
  v = fmaf(x1, M[DPROJ+j], v);
  v = fmaf(x2, M[2*DPROJ+j], v);
  float tt = v + dt_bias[h];
  float dtv = (tt > 20.f) ? tt : log1pf(__expf(tt));
  ((float*)(wsb+OFF_DT))[(size_t)r*16 + h] = dtv;
  __shared__ float s[128];
  float A2 = -__expf(A_log[h]) * LOG2E;   // cum kept in log2 units
  s[t] = dtv * A2; __syncthreads();
  for (int off=1; off<128; off<<=1){
    float sv = (t>=off) ? s[t-off] : 0.f;
    __syncthreads();
    s[t] += sv;
    __syncthreads();
  }
  ((float*)(wsb + OFF_CUM))[(size_t)bi*128 + t] = s[t];
  if (t==127) ((float*)(wsb + OFF_CDC))[bi] = exp2f(s[127]);
}

// ------- K4a: CB = C·B^T via MFMA -> cbt tiled [grp][t][e] ----------------------
__global__ __launch_bounds__(256) void k4a_cb(char* __restrict__ wsb){
  int bi = blockIdx.x;                    // (b*64+c)*4 + squad
  int sq = bi & 3; int bc = bi >> 2;
  __shared__ __align__(16) char sC[16384];   // C[128][64] bf16 swizzled rows(128B)
  __shared__ __align__(16) char sB[4096];    // B[32][64]  bf16 swizzled
  const ushort* bcm = (const ushort*)(wsb + OFF_BCM);
  ushort* cbtT = (ushort*)(wsb + OFF_CBT) + (size_t)bc*16384;
  size_t rb = (size_t)bc*128;
  int tid = threadIdx.x;
  int lane = tid&63, wid = tid>>6, l15 = lane&15, l4 = lane>>4;
  int s_base = sq*32;
  f32x4 acc[2][2] = {};
  for (int nt = 0; nt < 4; ++nt){
    int n0 = nt*64;
    __syncthreads();
    for (int idx = tid; idx < 1024; idx += 256){
      int t = idx>>3, c = idx&7;
      uint4 v = *(const uint4*)(bcm + (rb+t)*512 + 256 + n0 + c*8);
      *(uint4*)(sC + ((t*128 + c*16) ^ ((t&7)<<4))) = v;
    }
    {
      int idx = tid;
      int s = idx>>3, c = idx&7;
      uint4 v = *(const uint4*)(bcm + (rb+s_base+s)*512 + n0 + c*8);
      *(uint4*)(sB + ((s*128 + c*16) ^ ((s&7)<<4))) = v;
    }
    __syncthreads();
    #pragma unroll
    for (int ks = 0; ks < 2; ++ks){
      int kb = ks*64 + l4*16;
      int t0 = wid*32 + l15, t1 = t0 + 16;
      short8 a0 = *(const short8*)(sC + ((t0*128 + kb) ^ ((t0&7)<<4)));
      short8 a1 = *(const short8*)(sC + ((t1*128 + kb) ^ ((t1&7)<<4)));
      short8 b0 = *(const short8*)(sB + ((l15*128 + kb) ^ ((l15&7)<<4)));
      short8 b1 = *(const short8*)(sB + (((16+l15)*128 + kb) ^ (((16+l15)&7)<<4)));
      acc[0][0] = MFMA16(a0,b0,acc[0][0]);
      acc[0][1] = MFMA16(a0,b1,acc[0][1]);
      acc[1][0] = MFMA16(a1,b0,acc[1][0]);
      acc[1][1] = MFMA16(a1,b1,acc[1][1]);
    }
  }
  #pragma unroll
  for (int mt=0; mt<2; ++mt)
  #pragma unroll
  for (int st=0; st<2; ++st)
  #pragma unroll
  for (int r=0; r<4; ++r){
    int t = wid*32 + mt*16 + l4*4 + r;
    int s = s_base + st*16 + l15;
    cbtT[(size_t)((s>>3)*128 + t)*8 + (s&7)] = f2bf(acc[mt][st][r]);
  }
}

// -------- K4s: states = (x*w)^T @ B, frags direct from global -------------------
__global__ __launch_bounds__(256) void k4s_states(char* __restrict__ wsb){
  int bc, h; swz2048(blockIdx.x, bc, h);
  int bi = bc*16 + h;
  __shared__ float sW[128];
  const ushort* xt  = (const ushort*)(wsb + OFF_XT) + (size_t)bi*4096;
  const ushort* btb = (const ushort*)(wsb + OFF_BT) + (size_t)bc*32768;
  const float* cum  = (const float*)(wsb + OFF_CUM) + (size_t)bi*128;
  const float* dtp  = (const float*)(wsb + OFF_DT);
  ushort* st = (ushort*)(wsb + OFF_ST) + (size_t)bi*8192;
  size_t rb = (size_t)bc*128;
  int tid = threadIdx.x;
  if (tid < 128){
    float c127 = cum[127];
    sW[tid] = exp2f(c127 - cum[tid]) * dtp[(rb+tid)*16 + h];
  }
  __syncthreads();
  int lane = tid&63, wid = tid>>6, l15 = lane&15, l4 = lane>>4;
  f32x4 acc2[2][4] = {};
  #pragma unroll
  for (int ks = 0; ks < 4; ++ks){
    int grp = ks*4 + l4;
    const float* wp = sW + grp*8;
    short8 ra0 = *(const short8*)(xt + (size_t)(grp*32 + l15)*8);
    short8 ra1 = *(const short8*)(xt + (size_t)(grp*32 + 16 + l15)*8);
    short8 a0, a1;
    #pragma unroll
    for (int j=0;j<8;++j){
      a0[j] = (short)f2bf(bf2f((ushort)ra0[j]) * wp[j]);
      a1[j] = (short)f2bf(bf2f((ushort)ra1[j]) * wp[j]);
    }
    #pragma unroll
    for (int ntl = 0; ntl < 4; ++ntl){
      int n = wid*64 + ntl*16 + l15;
      short8 b = *(const short8*)(btb + (size_t)(grp*256 + n)*8);
      acc2[0][ntl] = MFMA16(a0,b,acc2[0][ntl]);
      acc2[1][ntl] = MFMA16(a1,b,acc2[1][ntl]);
    }
  }
  #pragma unroll
  for (int mt=0; mt<2; ++mt)
  #pragma unroll
  for (int ntl=0; ntl<4; ++ntl)
  #pragma unroll
  for (int r=0; r<4; ++r){
    int p = mt*16 + l4*4 + r;
    int n = wid*64 + ntl*16 + l15;
    st[(size_t)((n>>3)*32 + p)*8 + (n&7)] = f2bf(acc2[mt][ntl][r]);
  }
}

// ---------------- K5: sequential chunk scan (tiled ST, in place) ----------------
__global__ __launch_bounds__(256) void k5_scan(char* __restrict__ wsb){
  int g = blockIdx.x*256 + threadIdx.x;   // 262144 threads
  int l = g & 63;
  int e = l & 7, plow = l >> 3;
  int up = g >> 6;
  int p = (up & 3)*8 + plow; up >>= 2;
  int grp = up & 31; up >>= 5;
  int h = up & 15; int b = up >> 4;
  int off = (grp*32 + p)*8 + e;
  ushort* st = (ushort*)(wsb + OFF_ST);
  const float* cdc = (const float*)(wsb + OFF_CDC);
  float S = 0.f;
  for (int c=0; c<64; ++c){
    int bi = (b*64+c)*16 + h;
    size_t idx = (size_t)bi*8192 + off;
    float v = bf2f(st[idx]);
    st[idx] = f2bf(S);
    S = fmaf(S, cdc[bi], v);
  }
}

// -------- K4y: y = attn@x + exp2(cum)*C@prev + D*x -> Y bf16 --------------------
__global__ __launch_bounds__(256) void k4y_out(const float* __restrict__ Dp,
                                               char* __restrict__ wsb){
  int bc, h; swz2048(blockIdx.x, bc, h);
  int bi = bc*16 + h;
  __shared__ float sCum[128], sDt[128], sE[128];
  const ushort* cbt = (const ushort*)(wsb + OFF_CBT) + (size_t)bc*16384;
  const ushort* xt  = (const ushort*)(wsb + OFF_XT) + (size_t)bi*4096;
  const ushort* bcm = (const ushort*)(wsb + OFF_BCM);
  const ushort* prev= (const ushort*)(wsb + OFF_ST) + (size_t)bi*8192;
  const float* cum  = (const float*)(wsb + OFF_CUM) + (size_t)bi*128;
  const float* dtp  = (const float*)(wsb + OFF_DT);
  ushort* Yb = (ushort*)(wsb + OFF_Y);
  size_t rb = (size_t)bc*128;
  int tid = threadIdx.x;
  if (tid < 128){
    float cv = cum[tid];
    sCum[tid] = cv;
    sDt[tid]  = dtp[(rb+tid)*16 + h];
    sE[tid]   = exp2f(cv);
  }
  __syncthreads();
  int lane = tid&63, wid = tid>>6, l15 = lane&15, l4 = lane>>4;
  int t0 = wid*32 + l15, t1 = t0 + 16;
  float ct0 = sCum[t0], ct1 = sCum[t1];
  // ---- y_intra: A = CB*decay*dt built in-register, B = xT frags ----
  f32x4 acc[2][2] = {};
  #pragma unroll
  for (int ks = 0; ks < 4; ++ks){
    int grp = ks*4 + l4;
    int s0 = grp*8;
    short8 ra0 = *(const short8*)(cbt + (size_t)(grp*128 + t0)*8);
    short8 ra1 = *(const short8*)(cbt + (size_t)(grp*128 + t1)*8);
    short8 a0, a1;
    #pragma unroll
    for (int j=0;j<8;++j){
      int s = s0 + j;
      float cs = sCum[s], ds = sDt[s];
      float e0 = exp2f(fminf(ct0 - cs, 0.f)) * ds;
      float e1 = exp2f(fminf(ct1 - cs, 0.f)) * ds;
      float v0 = (t0 >= s) ? bf2f((ushort)ra0[j]) * e0 : 0.f;
      float v1 = (t1 >= s) ? bf2f((ushort)ra1[j]) * e1 : 0.f;
      a0[j] = (short)f2bf(v0);
      a1[j] = (short)f2bf(v1);
    }
    short8 b0 = *(const short8*)(xt + (size_t)(grp*32 + l15)*8);
    short8 b1 = *(const short8*)(xt + (size_t)(grp*32 + 16 + l15)*8);
    acc[0][0] = MFMA16(a0,b0,acc[0][0]);
    acc[0][1] = MFMA16(a0,b1,acc[0][1]);
    acc[1][0] = MFMA16(a1,b0,acc[1][0]);
    acc[1][1] = MFMA16(a1,b1,acc[1][1]);
  }
  // ---- y_inter = C @ prev^T : K=n(256) ----
  f32x4 acc2[2][2] = {};
  #pragma unroll
  for (int ks = 0; ks < 8; ++ks){
    int koff = ks*32 + l4*8;
    int grp = ks*4 + l4;
    short8 a0 = *(const short8*)(bcm + (rb+t0)*512 + 256 + koff);
    short8 a1 = *(const short8*)(bcm + (rb+t1)*512 + 256 + koff);
    short8 b0 = *(const short8*)(prev + (size_t)(grp*32 + l15)*8);
    short8 b1 = *(const short8*)(prev + (size_t)(grp*32 + 16 + l15)*8);
    acc2[0][0] = MFMA16(a0,b0,acc2[0][0]);
    acc2[0][1] = MFMA16(a0,b1,acc2[0][1]);
    acc2[1][0] = MFMA16(a1,b0,acc2[1][0]);
    acc2[1][1] = MFMA16(a1,b1,acc2[1][1]);
  }
  float Dh = Dp[h];
  #pragma unroll
  for (int mt=0; mt<2; ++mt){
    int tb = wid*32 + mt*16 + l4*4;
    int tg = tb>>3, e0i = tb&7;
    #pragma unroll
    for (int nt=0; nt<2; ++nt){
      int p = nt*16 + l15;
      ushort xv[4];
      *(uint2*)xv = *(const uint2*)(xt + (size_t)(tg*32 + p)*8 + e0i);
      #pragma unroll
      for (int r=0; r<4; ++r){
        int t = tb + r;
        float yv = acc[mt][nt][r] + sE[t]*acc2[mt][nt][r] + Dh*bf2f(xv[r]);
        Yb[(rb+t)*512 + h*32 + p] = f2bf(yv);
      }
    }
  }
}

// ---------------- K7: gate(silu(z)) -> RMS -> out_proj (MFMA) -------------------
__global__ __launch_bounds__(256) void k7_final(const float* __restrict__ x,
                                                char* __restrict__ wsb,
                                                float* __restrict__ out){
  int r0 = blockIdx.x*32;                  // 512 blocks
  __shared__ __align__(16) char sG[32768]; // G[32][512] bf16 rows 1024B, swizzled
  __shared__ float sScale[32];
  const ushort* Yb = (const ushort*)(wsb + OFF_Y);
  const float* M  = (const float*)(wsb + OFF_M);
  const float* Cb = (const float*)(wsb + OFF_CB_B);
  const ushort* WT = (const ushort*)(wsb + OFF_WT);
  int tid = threadIdx.x;
  int r = tid>>3, li = tid&7;
  int row = r0 + r; int b = row>>13, l = row & 8191;
  int hh, wv;
  if (l < 4096){ hh = l>>6; wv = l&63; }
  else { int l2 = l-4096; hh = 63-(l2>>6); wv = 63-(l2&63); }
  const float* xb = x + (size_t)b*12288;
  float x0 = xb[hh*64+wv], x1 = xb[4096+hh*64+wv], x2 = xb[8192+hh*64+wv];
  float sq = 0.f;
  #pragma unroll
  for (int k = 0; k < 8; ++k){
    int i0 = li*64 + k*8;
    short8 yv = *(const short8*)(Yb + (size_t)row*512 + i0);
    ushort g8[8];
    #pragma unroll
    for (int j=0;j<8;++j){
      int i = i0 + j;
      float z = Cb[i];
      z = fmaf(x0, M[i], z);
      z = fmaf(x1, M[DPROJ+i], z);
      z = fmaf(x2, M[2*DPROJ+i], z);
      float g = bf2f((ushort)yv[j]) * z * sigm(z);
      sq = fmaf(g, g, sq);
      g8[j] = f2bf(g);
    }
    *(uint4*)(sG + ((r*1024 + i0*2) ^ ((r&7)<<4))) = *(uint4*)g8;
  }
  sq += __shfl_xor(sq, 1, 64);
  sq += __shfl_xor(sq, 2, 64);
  sq += __shfl_xor(sq, 4, 64);
  if (li == 0) sScale[r] = rsqrtf(sq*(1.f/512.f) + 1e-5f);
  __syncthreads();
  int lane = tid&63, wid = tid>>6, l15 = lane&15, l4 = lane>>4;
  f32x4 acc[2][2] = {};
  #pragma unroll
  for (int ks = 0; ks < 16; ++ks){
    int kb = ks*64 + l4*16;
    int rr0 = l15, rr1 = 16+l15;
    short8 a0 = *(const short8*)(sG + ((rr0*1024 + kb) ^ ((rr0&7)<<4)));
    short8 a1 = *(const short8*)(sG + ((rr1*1024 + kb) ^ ((rr1&7)<<4)));
    int koff = ks*32 + l4*8;
    short8 b0 = *(const short8*)(WT + (size_t)(wid*32 + l15)*512 + koff);
    short8 b1 = *(const short8*)(WT + (size_t)(wid*32 + 16 + l15)*512 + koff);
    acc[0][0] = MFMA16(a0,b0,acc[0][0]);
    acc[0][1] = MFMA16(a0,b1,acc[0][1]);
    acc[1][0] = MFMA16(a1,b0,acc[1][0]);
    acc[1][1] = MFMA16(a1,b1,acc[1][1]);
  }
  #pragma unroll
  for (int mt=0; mt<2; ++mt)
  #pragma unroll
  for (int nt=0; nt<2; ++nt)
  #pragma unroll
  for (int r4=0; r4<4; ++r4){
    int rr = mt*16 + l4*4 + r4;
    int d = wid*32 + nt*16 + l15;
    out[(size_t)(r0+rr)*128 + d] = acc[mt][nt][r4] * sScale[rr];
  }
}

extern "C" void kernel_launch(void* const* d_in, const int* in_sizes, int n_in,
                              void* d_out, int out_size, void* d_ws, size_t ws_size,
                              hipStream_t stream) {
  const float* x         = (const float*)d_in[0];
  const float* fc0_w     = (const float*)d_in[1];
  const float* fc0_b     = (const float*)d_in[2];
  const float* in_proj_w = (const float*)d_in[3];
  const float* conv_w    = (const float*)d_in[4];
  const float* conv_b    = (const float*)d_in[5];
  const float* dt_bias   = (const float*)d_in[6];
  const float* A_log     = (const float*)d_in[7];
  const float* Dp        = (const float*)d_in[8];
  const float* norm_w    = (const float*)d_in[9];
  const float* out_proj_w= (const float*)d_in[10];
  char* wsb  = (char*)d_ws;
  float* out = (float*)d_out;

  k0_prep<<<dim3(7),     dim3(256), 0, stream>>>(fc0_w, fc0_b, in_proj_w, wsb);
  k0b_wt <<<dim3(128),   dim3(256), 0, stream>>>(norm_w, out_proj_w, wsb);
  k12_projconv<<<dim3(1024), dim3(256), 0, stream>>>(x, conv_w, conv_b, wsb);
  k3_cum <<<dim3(2048),  dim3(128), 0, stream>>>(x, dt_bias, A_log, wsb);
  k4a_cb <<<dim3(512),   dim3(256), 0, stream>>>(wsb);
  k4s_states<<<dim3(2048), dim3(256), 0, stream>>>(wsb);
  k5_scan<<<dim3(1024),  dim3(256), 0, stream>>>(wsb);
  k4y_out<<<dim3(2048),  dim3(256), 0, stream>>>(Dp, wsb);
  k7_final<<<dim3(512),  dim3(256), 0, stream>>>(x, wsb, out);
}

// Round 9
// 146.236 us; speedup vs baseline: 2.5481x; 1.0508x over previous
//
#include <hip/hip_runtime.h>

typedef short short8 __attribute__((ext_vector_type(8)));
typedef float f32x4 __attribute__((ext_vector_type(4)));
typedef unsigned short ushort;
typedef unsigned int uint;

#define MFMA16(a,b,c) __builtin_amdgcn_mfma_f32_16x16x32_bf16(a,b,c,0,0,0)
#define DPROJ 1552
#define LOG2E 1.44269504f

// ---- workspace byte offsets ----
constexpr size_t OFF_M    = 0;                         // 3*1552 f32
constexpr size_t OFF_CB_B = 0x5000;                    // 1552 f32
constexpr size_t OFF_WT   = 0x8000;                    // 128*512 bf16
constexpr size_t OFF_XT   = 0x30000;                   // [bc128][h16][grp16][p32][e8] u16 = 16 MB
constexpr size_t OFF_DT   = OFF_XT  + 16777216ull;     // 16384*16 f32
constexpr size_t OFF_BCM  = OFF_DT  + 1048576ull;      // [row][512] u16 (B|C)
constexpr size_t OFF_CUM  = OFF_BCM + 16777216ull;     // 2048*128 f32 (log2 units)
constexpr size_t OFF_CDC  = OFF_CUM + 1048576ull;      // 2048 f32
constexpr size_t OFF_CBT  = OFF_CDC + 8192ull;         // [bc][grp16][t128][e8] u16, PRE-MASKED
constexpr size_t OFF_BT   = OFF_CBT + 4194304ull;      // [bc][grp16][n256][e8] u16 = 8 MB
constexpr size_t OFF_ST   = OFF_BT  + 8388608ull;      // [bi][grp32][p32][e8] u16 = 32 MB
constexpr size_t OFF_Y    = OFF_ST  + 33554432ull;     // 16384*512 bf16

__device__ __forceinline__ float sigm(float x){ return 1.0f/(1.0f + __expf(-x)); }
__device__ __forceinline__ ushort f2bf(float f){
  union { float f; uint u; } c; c.f = f;
  uint u = c.u;
  return (ushort)((u + 0x7FFFu + ((u>>16)&1u)) >> 16);
}
__device__ __forceinline__ float bf2f(ushort h){
  union { uint u; float f; } c; c.u = ((uint)h)<<16;
  return c.f;
}
// XCD swizzle for 2048-block grids: all 16 heads of one (b,c) on one XCD
__device__ __forceinline__ void swz2048(int p, int& bc, int& h){
  int xcd = p & 7, slot = p >> 3;
  bc = xcd*16 + (slot >> 4);
  h  = slot & 15;
}

// ------- K0m: fuse fc0 into in_proj + WoutT'[d][i] = norm_w[i]*Wout[i][d] -------
__global__ __launch_bounds__(256) void k0m_prep(const float* __restrict__ fc0_w,
                                                const float* __restrict__ fc0_b,
                                                const float* __restrict__ W,
                                                const float* __restrict__ norm_w,
                                                const float* __restrict__ Wout,
                                                char* __restrict__ wsb){
  int d = blockIdx.x;                     // 128 blocks
  ushort* WT = (ushort*)(wsb + OFF_WT);
  for (int i = threadIdx.x; i < 512; i += 256)
    WT[(size_t)d*512 + i] = f2bf(norm_w[i]*Wout[(size_t)i*128 + d]);
  if (d < 7){
    int j = d*256 + threadIdx.x;
    if (j >= DPROJ) return;
    float* Mo = (float*)(wsb + OFF_M);
    float* Co = (float*)(wsb + OFF_CB_B);
    float m0=0.f,m1=0.f,m2=0.f,cc=0.f;
    for (int dd=0; dd<128; ++dd){
      float w = W[(size_t)dd*DPROJ + j];
      m0 = fmaf(fc0_w[dd],     w, m0);
      m1 = fmaf(fc0_w[128+dd], w, m1);
      m2 = fmaf(fc0_w[256+dd], w, m2);
      cc = fmaf(fc0_b[dd],     w, cc);
    }
    Mo[j] = m0; Mo[DPROJ + j] = m1; Mo[2*DPROJ + j] = m2;
    Co[j] = cc;
  }
}

// ------ K12: fused proj+causal conv(4)+silu -> xT tiled / BC row / BT tiled -----
__device__ __forceinline__ void proj8(int li, const float* __restrict__ xb,
                                      const float* m0, const float* m1, const float* m2,
                                      const float* c8, float* dst){
  if (li < 0){
    #pragma unroll
    for (int j=0;j<8;++j) dst[j] = 0.f;
    return;
  }
  int hh, wv;
  if (li < 4096){ hh = li>>6; wv = li&63; }
  else { int l2 = li-4096; hh = 63-(l2>>6); wv = 63-(l2&63); }
  float x0 = xb[hh*64+wv], x1 = xb[4096+hh*64+wv], x2 = xb[8192+hh*64+wv];
  #pragma unroll
  for (int j=0;j<8;++j)
    dst[j] = fmaf(x2, m2[j], fmaf(x1, m1[j], fmaf(x0, m0[j], c8[j])));
}

__device__ __forceinline__ void conv8(const float* cb8, const float* cw0, const float* cw1,
                                      const float* cw2, const float* cw3,
                                      const float* wA, const float* wB,
                                      const float* wC, const float* wD, ushort* o){
  #pragma unroll
  for (int j=0;j<8;++j){
    float a = cb8[j];
    a = fmaf(wA[j], cw0[j], a);
    a = fmaf(wB[j], cw1[j], a);
    a = fmaf(wC[j], cw2[j], a);
    a = fmaf(wD[j], cw3[j], a);
    o[j] = f2bf(a * sigm(a));
  }
}

__global__ __launch_bounds__(256) void k12_projconv(const float* __restrict__ x,
                                                    const float* __restrict__ conv_w,
                                                    const float* __restrict__ conv_b,
                                                    char* __restrict__ wsb){
  int tid = threadIdx.x;
  int cg = tid & 127, rl = tid >> 7;
  int row0 = blockIdx.x*16 + rl*8;        // 1024 blocks, 16 rows each
  int b = row0 >> 13, l0 = row0 & 8191;
  const float* M  = (const float*)(wsb + OFF_M);
  const float* Cc = (const float*)(wsb + OFF_CB_B);
  const float* xb = x + (size_t)b*12288;
  int ch0 = cg*8, j0 = 512 + ch0;
  float m0[8],m1[8],m2[8],c8[8],cw0[8],cw1[8],cw2[8],cw3[8],cb8[8];
  #pragma unroll
  for (int j=0;j<8;++j){
    m0[j]=M[j0+j]; m1[j]=M[DPROJ+j0+j]; m2[j]=M[2*DPROJ+j0+j]; c8[j]=Cc[j0+j];
    cw0[j]=conv_w[(ch0+j)*4+0]; cw1[j]=conv_w[(ch0+j)*4+1];
    cw2[j]=conv_w[(ch0+j)*4+2]; cw3[j]=conv_w[(ch0+j)*4+3];
    cb8[j]=conv_b[ch0+j];
  }
  bool is_xs = (ch0 < 512);
  bool is_b  = (ch0 >= 512) && (ch0 < 768);
  bool pack  = is_xs || is_b;
  ushort* bcmp = (ushort*)(wsb + OFF_BCM);
  int chb = ch0 - 512;
  uint colw[8][4];        // [ch j][row-pair] packed bf16x2, static idx only
  ushort oprev[8];
  float w0[8],w1[8],w2[8],w3[8];
  ushort o[8];
  proj8(l0-3, xb, m0,m1,m2,c8, w1);
  proj8(l0-2, xb, m0,m1,m2,c8, w2);
  proj8(l0-1, xb, m0,m1,m2,c8, w3);

#define ROW_EVEN(R, WN, WA, WB, WC)                                          \
  proj8(l0+R, xb, m0,m1,m2,c8, WN);                                          \
  conv8(cb8,cw0,cw1,cw2,cw3, WA,WB,WC,WN, o);                                \
  if (pack){ _Pragma("unroll")                                               \
    for (int j=0;j<8;++j) oprev[j] = o[j]; }                                 \
  if (!is_xs) *(uint4*)(bcmp + (size_t)(row0+R)*512 + chb) = *(uint4*)o;
#define ROW_ODD(R, WN, WA, WB, WC)                                           \
  proj8(l0+R, xb, m0,m1,m2,c8, WN);                                          \
  conv8(cb8,cw0,cw1,cw2,cw3, WA,WB,WC,WN, o);                                \
  if (pack){ _Pragma("unroll")                                               \
    for (int j=0;j<8;++j) colw[j][(R)>>1] = (uint)oprev[j] | ((uint)o[j]<<16); } \
  if (!is_xs) *(uint4*)(bcmp + (size_t)(row0+R)*512 + chb) = *(uint4*)o;

  ROW_EVEN(0, w0, w1,w2,w3)
  ROW_ODD (1, w1, w2,w3,w0)
  ROW_EVEN(2, w2, w3,w0,w1)
  ROW_ODD (3, w3, w0,w1,w2)
  ROW_EVEN(4, w0, w1,w2,w3)
  ROW_ODD (5, w1, w2,w3,w0)
  ROW_EVEN(6, w2, w3,w0,w1)
  ROW_ODD (7, w3, w0,w1,w2)
#undef ROW_EVEN
#undef ROW_ODD

  int bc = row0>>7, grp = (row0&127)>>3;
  if (is_xs){
    int h = ch0>>5, p0 = ch0&31;
    ushort* dst = (ushort*)(wsb+OFF_XT) + (((size_t)(bc*16+h)*16 + grp)*32)*8;
    #pragma unroll
    for (int j=0;j<8;++j){
      uint4 v; v.x = colw[j][0]; v.y = colw[j][1]; v.z = colw[j][2]; v.w = colw[j][3];
      *(uint4*)(dst + (size_t)(p0+j)*8) = v;
    }
  } else if (is_b){
    // BT tiled: [bc][grp16][n256][e8]
    ushort* btb = (ushort*)(wsb+OFF_BT) + (size_t)bc*32768;
    #pragma unroll
    for (int j=0;j<8;++j){
      uint4 v; v.x = colw[j][0]; v.y = colw[j][1]; v.z = colw[j][2]; v.w = colw[j][3];
      *(uint4*)(btb + (size_t)(grp*256 + chb + j)*8) = v;
    }
  }
}

// ------- K4a: CB = C·B^T via MFMA -> cbt tiled, PRE-MASKED (t<s -> 0) -----------
__global__ __launch_bounds__(256) void k4a_cb(char* __restrict__ wsb){
  int bi = blockIdx.x;                    // (b*64+c)*4 + squad
  int sq = bi & 3; int bc = bi >> 2;
  __shared__ __align__(16) char sC[16384];   // C[128][64] bf16 swizzled rows(128B)
  __shared__ __align__(16) char sB[4096];    // B[32][64]  bf16 swizzled
  const ushort* bcm = (const ushort*)(wsb + OFF_BCM);
  ushort* cbtT = (ushort*)(wsb + OFF_CBT) + (size_t)bc*16384;
  size_t rb = (size_t)bc*128;
  int tid = threadIdx.x;
  int lane = tid&63, wid = tid>>6, l15 = lane&15, l4 = lane>>4;
  int s_base = sq*32;
  f32x4 acc[2][2] = {};
  for (int nt = 0; nt < 4; ++nt){
    int n0 = nt*64;
    __syncthreads();
    for (int idx = tid; idx < 1024; idx += 256){
      int t = idx>>3, c = idx&7;
      uint4 v = *(const uint4*)(bcm + (rb+t)*512 + 256 + n0 + c*8);
      *(uint4*)(sC + ((t*128 + c*16) ^ ((t&7)<<4))) = v;
    }
    {
      int idx = tid;
      int s = idx>>3, c = idx&7;
      uint4 v = *(const uint4*)(bcm + (rb+s_base+s)*512 + n0 + c*8);
      *(uint4*)(sB + ((s*128 + c*16) ^ ((s&7)<<4))) = v;
    }
    __syncthreads();
    if (wid >= sq){   // triangle trim: wave's t-range below s-range -> all masked
      #pragma unroll
      for (int ks = 0; ks < 2; ++ks){
        int kb = ks*64 + l4*16;
        int t0 = wid*32 + l15, t1 = t0 + 16;
        short8 a0 = *(const short8*)(sC + ((t0*128 + kb) ^ ((t0&7)<<4)));
        short8 a1 = *(const short8*)(sC + ((t1*128 + kb) ^ ((t1&7)<<4)));
        short8 b0 = *(const short8*)(sB + ((l15*128 + kb) ^ ((l15&7)<<4)));
        short8 b1 = *(const short8*)(sB + (((16+l15)*128 + kb) ^ (((16+l15)&7)<<4)));
        acc[0][0] = MFMA16(a0,b0,acc[0][0]);
        acc[0][1] = MFMA16(a0,b1,acc[0][1]);
        acc[1][0] = MFMA16(a1,b0,acc[1][0]);
        acc[1][1] = MFMA16(a1,b1,acc[1][1]);
      }
    }
  }
  #pragma unroll
  for (int mt=0; mt<2; ++mt)
  #pragma unroll
  for (int st=0; st<2; ++st)
  #pragma unroll
  for (int r=0; r<4; ++r){
    int t = wid*32 + mt*16 + l4*4 + r;
    int s = s_base + st*16 + l15;
    float v = (t >= s) ? acc[mt][st][r] : 0.f;   // pre-mask upper triangle
    cbtT[(size_t)((s>>3)*128 + t)*8 + (s&7)] = f2bf(v);
  }
}

// -- K4sc: dt-proj + cumsum (was k3) + states = (x*w)^T @ B ----------------------
__global__ __launch_bounds__(256) void k4sc_states(const float* __restrict__ x,
                                                   const float* __restrict__ dt_bias,
                                                   const float* __restrict__ A_log,
                                                   char* __restrict__ wsb){
  int bc, h; swz2048(blockIdx.x, bc, h);
  int bi = bc*16 + h;
  __shared__ float sCS[128];
  __shared__ float sW[128];
  const ushort* xt  = (const ushort*)(wsb + OFF_XT) + (size_t)bi*4096;
  const ushort* btb = (const ushort*)(wsb + OFF_BT) + (size_t)bc*32768;
  ushort* st = (ushort*)(wsb + OFF_ST) + (size_t)bi*8192;
  int tid = threadIdx.x;
  // --- dt projection + store (fused old k3) ---
  float dtv = 0.f;
  if (tid < 128){
    int r = bc*128 + tid;
    int b = r >> 13, l = r & 8191;
    int hp, wv;
    if (l < 4096){ hp = l>>6; wv = l&63; }
    else { int l2 = l-4096; hp = 63-(l2>>6); wv = 63-(l2&63); }
    const float* xb = x + (size_t)b*12288;
    float x0 = xb[hp*64+wv], x1 = xb[4096+hp*64+wv], x2 = xb[8192+hp*64+wv];
    const float* M  = (const float*)(wsb + OFF_M);
    const float* Cc = (const float*)(wsb + OFF_CB_B);
    int j = 1536 + h;
    float v = Cc[j];
    v = fmaf(x0, M[j], v);
    v = fmaf(x1, M[DPROJ+j], v);
    v = fmaf(x2, M[2*DPROJ+j], v);
    float tt = v + dt_bias[h];
    dtv = (tt > 20.f) ? tt : log1pf(__expf(tt));
    ((float*)(wsb+OFF_DT))[(size_t)r*16 + h] = dtv;
    float A2 = -__expf(A_log[h]) * LOG2E;
    sCS[tid] = dtv * A2;
  }
  __syncthreads();
  for (int off=1; off<128; off<<=1){
    float sv = (tid>=off && tid<128) ? sCS[tid-off] : 0.f;
    __syncthreads();
    if (tid < 128) sCS[tid] += sv;
    __syncthreads();
  }
  if (tid < 128){
    float cv = sCS[tid];
    ((float*)(wsb + OFF_CUM))[(size_t)bi*128 + tid] = cv;
    if (tid == 127) ((float*)(wsb + OFF_CDC))[bi] = exp2f(cv);
  }
  __syncthreads();
  if (tid < 128) sW[tid] = exp2f(sCS[127] - sCS[tid]) * dtv;
  __syncthreads();
  // --- states MFMA ---
  int lane = tid&63, wid = tid>>6, l15 = lane&15, l4 = lane>>4;
  f32x4 acc2[2][4] = {};
  #pragma unroll
  for (int ks = 0; ks < 4; ++ks){
    int grp = ks*4 + l4;
    const float* wp = sW + grp*8;
    short8 ra0 = *(const short8*)(xt + (size_t)(grp*32 + l15)*8);
    short8 ra1 = *(const short8*)(xt + (size_t)(grp*32 + 16 + l15)*8);
    short8 a0, a1;
    #pragma unroll
    for (int j=0;j<8;++j){
      a0[j] = (short)f2bf(bf2f((ushort)ra0[j]) * wp[j]);
      a1[j] = (short)f2bf(bf2f((ushort)ra1[j]) * wp[j]);
    }
    #pragma unroll
    for (int ntl = 0; ntl < 4; ++ntl){
      int n = wid*64 + ntl*16 + l15;
      short8 b = *(const short8*)(btb + (size_t)(grp*256 + n)*8);
      acc2[0][ntl] = MFMA16(a0,b,acc2[0][ntl]);
      acc2[1][ntl] = MFMA16(a1,b,acc2[1][ntl]);
    }
  }
  #pragma unroll
  for (int mt=0; mt<2; ++mt)
  #pragma unroll
  for (int ntl=0; ntl<4; ++ntl)
  #pragma unroll
  for (int r=0; r<4; ++r){
    int p = mt*16 + l4*4 + r;
    int n = wid*64 + ntl*16 + l15;
    st[(size_t)((n>>3)*32 + p)*8 + (n&7)] = f2bf(acc2[mt][ntl][r]);
  }
}

// ---------------- K5: sequential chunk scan (tiled ST, in place) ----------------
__global__ __launch_bounds__(256) void k5_scan(char* __restrict__ wsb){
  int g = blockIdx.x*256 + threadIdx.x;   // 262144 threads
  int l = g & 63;
  int e = l & 7, plow = l >> 3;
  int up = g >> 6;
  int p = (up & 3)*8 + plow; up >>= 2;
  int grp = up & 31; up >>= 5;
  int h = up & 15; int b = up >> 4;
  int off = (grp*32 + p)*8 + e;
  ushort* st = (ushort*)(wsb + OFF_ST);
  const float* cdc = (const float*)(wsb + OFF_CDC);
  float S = 0.f;
  for (int c=0; c<64; ++c){
    int bi = (b*64+c)*16 + h;
    size_t idx = (size_t)bi*8192 + off;
    float v = bf2f(st[idx]);
    st[idx] = f2bf(S);
    S = fmaf(S, cdc[bi], v);
  }
}

// -------- K4y: y = attn@x + exp2(cum)*C@prev + D*x -> Y bf16 --------------------
__global__ __launch_bounds__(256) void k4y_out(const float* __restrict__ Dp,
                                               char* __restrict__ wsb){
  int bc, h; swz2048(blockIdx.x, bc, h);
  int bi = bc*16 + h;
  __shared__ float sCum[128], sDt[128], sE[128];
  const ushort* cbt = (const ushort*)(wsb + OFF_CBT) + (size_t)bc*16384;
  const ushort* xt  = (const ushort*)(wsb + OFF_XT) + (size_t)bi*4096;
  const ushort* bcm = (const ushort*)(wsb + OFF_BCM);
  const ushort* prev= (const ushort*)(wsb + OFF_ST) + (size_t)bi*8192;
  const float* cum  = (const float*)(wsb + OFF_CUM) + (size_t)bi*128;
  const float* dtp  = (const float*)(wsb + OFF_DT);
  ushort* Yb = (ushort*)(wsb + OFF_Y);
  size_t rb = (size_t)bc*128;
  int tid = threadIdx.x;
  if (tid < 128){
    float cv = cum[tid];
    sCum[tid] = cv;
    sDt[tid]  = dtp[(rb+tid)*16 + h];
    sE[tid]   = exp2f(cv);
  }
  __syncthreads();
  int lane = tid&63, wid = tid>>6, l15 = lane&15, l4 = lane>>4;
  int t0 = wid*32 + l15, t1 = t0 + 16;
  float ct0 = sCum[t0], ct1 = sCum[t1];
  // ---- y_intra: A = CBmask*decay*dt in-register; triangle-trimmed ks loop ----
  f32x4 acc[2][2] = {};
  #pragma unroll
  for (int ks = 0; ks < 4; ++ks){
    if (ks <= wid){   // wave-uniform: groups with s > wave's t-range are all-masked
      int grp = ks*4 + l4;
      int s0 = grp*8;
      short8 ra0 = *(const short8*)(cbt + (size_t)(grp*128 + t0)*8);
      short8 ra1 = *(const short8*)(cbt + (size_t)(grp*128 + t1)*8);
      short8 a0, a1;
      #pragma unroll
      for (int j=0;j<8;++j){
        int s = s0 + j;
        float cs = sCum[s], ds = sDt[s];
        float e0 = exp2f(fminf(ct0 - cs, 0.f)) * ds;   // clamp mandatory: 0*inf=NaN
        float e1 = exp2f(fminf(ct1 - cs, 0.f)) * ds;
        a0[j] = (short)f2bf(bf2f((ushort)ra0[j]) * e0);  // CBT pre-masked
        a1[j] = (short)f2bf(bf2f((ushort)ra1[j]) * e1);
      }
      short8 b0 = *(const short8*)(xt + (size_t)(grp*32 + l15)*8);
      short8 b1 = *(const short8*)(xt + (size_t)(grp*32 + 16 + l15)*8);
      acc[0][0] = MFMA16(a0,b0,acc[0][0]);
      acc[0][1] = MFMA16(a0,b1,acc[0][1]);
      acc[1][0] = MFMA16(a1,b0,acc[1][0]);
      acc[1][1] = MFMA16(a1,b1,acc[1][1]);
    }
  }
  // ---- y_inter = C @ prev^T : K=n(256) ----
  f32x4 acc2[2][2] = {};
  #pragma unroll
  for (int ks = 0; ks < 8; ++ks){
    int koff = ks*32 + l4*8;
    int grp = ks*4 + l4;
    short8 a0 = *(const short8*)(bcm + (rb+t0)*512 + 256 + koff);
    short8 a1 = *(const short8*)(bcm + (rb+t1)*512 + 256 + koff);
    short8 b0 = *(const short8*)(prev + (size_t)(grp*32 + l15)*8);
    short8 b1 = *(const short8*)(prev + (size_t)(grp*32 + 16 + l15)*8);
    acc2[0][0] = MFMA16(a0,b0,acc2[0][0]);
    acc2[0][1] = MFMA16(a0,b1,acc2[0][1]);
    acc2[1][0] = MFMA16(a1,b0,acc2[1][0]);
    acc2[1][1] = MFMA16(a1,b1,acc2[1][1]);
  }
  float Dh = Dp[h];
  #pragma unroll
  for (int mt=0; mt<2; ++mt){
    int tb = wid*32 + mt*16 + l4*4;
    int tg = tb>>3, e0i = tb&7;
    #pragma unroll
    for (int nt=0; nt<2; ++nt){
      int p = nt*16 + l15;
      ushort xv[4];
      *(uint2*)xv = *(const uint2*)(xt + (size_t)(tg*32 + p)*8 + e0i);
      #pragma unroll
      for (int r=0; r<4; ++r){
        int t = tb + r;
        float yv = acc[mt][nt][r] + sE[t]*acc2[mt][nt][r] + Dh*bf2f(xv[r]);
        Yb[(rb+t)*512 + h*32 + p] = f2bf(yv);
      }
    }
  }
}

// ---------------- K7: gate(silu(z)) -> RMS -> out_proj (MFMA) -------------------
__global__ __launch_bounds__(256) void k7_final(const float* __restrict__ x,
                                                char* __restrict__ wsb,
                                                float* __restrict__ out){
  int r0 = blockIdx.x*32;                  // 512 blocks
  __shared__ __align__(16) char sG[32768]; // G[32][512] bf16 rows 1024B, swizzled
  __shared__ float sScale[32];
  const ushort* Yb = (const ushort*)(wsb + OFF_Y);
  const float* M  = (const float*)(wsb + OFF_M);
  const float* Cb = (const float*)(wsb + OFF_CB_B);
  const ushort* WT = (const ushort*)(wsb + OFF_WT);
  int tid = threadIdx.x;
  int r = tid>>3, li = tid&7;
  int row = r0 + r; int b = row>>13, l = row & 8191;
  int hh, wv;
  if (l < 4096){ hh = l>>6; wv = l&63; }
  else { int l2 = l-4096; hh = 63-(l2>>6); wv = 63-(l2&63); }
  const float* xb = x + (size_t)b*12288;
  float x0 = xb[hh*64+wv], x1 = xb[4096+hh*64+wv], x2 = xb[8192+hh*64+wv];
  float sq = 0.f;
  #pragma unroll
  for (int k = 0; k < 8; ++k){
    int i0 = li*64 + k*8;
    short8 yv = *(const short8*)(Yb + (size_t)row*512 + i0);
    ushort g8[8];
    #pragma unroll
    for (int j=0;j<8;++j){
      int i = i0 + j;
      float z = Cb[i];
      z = fmaf(x0, M[i], z);
      z = fmaf(x1, M[DPROJ+i], z);
      z = fmaf(x2, M[2*DPROJ+i], z);
      float g = bf2f((ushort)yv[j]) * z * sigm(z);
      sq = fmaf(g, g, sq);
      g8[j] = f2bf(g);
    }
    *(uint4*)(sG + ((r*1024 + i0*2) ^ ((r&7)<<4))) = *(uint4*)g8;
  }
  sq += __shfl_xor(sq, 1, 64);
  sq += __shfl_xor(sq, 2, 64);
  sq += __shfl_xor(sq, 4, 64);
  if (li == 0) sScale[r] = rsqrtf(sq*(1.f/512.f) + 1e-5f);
  __syncthreads();
  int lane = tid&63, wid = tid>>6, l15 = lane&15, l4 = lane>>4;
  f32x4 acc[2][2] = {};
  #pragma unroll
  for (int ks = 0; ks < 16; ++ks){
    int kb = ks*64 + l4*16;
    int rr0 = l15, rr1 = 16+l15;
    short8 a0 = *(const short8*)(sG + ((rr0*1024 + kb) ^ ((rr0&7)<<4)));
    short8 a1 = *(const short8*)(sG + ((rr1*1024 + kb) ^ ((rr1&7)<<4)));
    int koff = ks*32 + l4*8;
    short8 b0 = *(const short8*)(WT + (size_t)(wid*32 + l15)*512 + koff);
    short8 b1 = *(const short8*)(WT + (size_t)(wid*32 + 16 + l15)*512 + koff);
    acc[0][0] = MFMA16(a0,b0,acc[0][0]);
    acc[0][1] = MFMA16(a0,b1,acc[0][1]);
    acc[1][0] = MFMA16(a1,b0,acc[1][0]);
    acc[1][1] = MFMA16(a1,b1,acc[1][1]);
  }
  #pragma unroll
  for (int mt=0; mt<2; ++mt)
  #pragma unroll
  for (int nt=0; nt<2; ++nt)
  #pragma unroll
  for (int r4=0; r4<4; ++r4){
    int rr = mt*16 + l4*4 + r4;
    int d = wid*32 + nt*16 + l15;
    out[(size_t)(r0+rr)*128 + d] = acc[mt][nt][r4] * sScale[rr];
  }
}

extern "C" void kernel_launch(void* const* d_in, const int* in_sizes, int n_in,
                              void* d_out, int out_size, void* d_ws, size_t ws_size,
                              hipStream_t stream) {
  const float* x         = (const float*)d_in[0];
  const float* fc0_w     = (const float*)d_in[1];
  const float* fc0_b     = (const float*)d_in[2];
  const float* in_proj_w = (const float*)d_in[3];
  const float* conv_w    = (const float*)d_in[4];
  const float* conv_b    = (const float*)d_in[5];
  const float* dt_bias   = (const float*)d_in[6];
  const float* A_log     = (const float*)d_in[7];
  const float* Dp        = (const float*)d_in[8];
  const float* norm_w    = (const float*)d_in[9];
  const float* out_proj_w= (const float*)d_in[10];
  char* wsb  = (char*)d_ws;
  float* out = (float*)d_out;

  k0m_prep<<<dim3(128),  dim3(256), 0, stream>>>(fc0_w, fc0_b, in_proj_w, norm_w, out_proj_w, wsb);
  k12_projconv<<<dim3(1024), dim3(256), 0, stream>>>(x, conv_w, conv_b, wsb);
  k4a_cb <<<dim3(512),   dim3(256), 0, stream>>>(wsb);
  k4sc_states<<<dim3(2048), dim3(256), 0, stream>>>(x, dt_bias, A_log, wsb);
  k5_scan<<<dim3(1024),  dim3(256), 0, stream>>>(wsb);
  k4y_out<<<dim3(2048),  dim3(256), 0, stream>>>(Dp, wsb);
  k7_final<<<dim3(512),  dim3(256), 0, stream>>>(x, wsb, out);
}

// Round 10
// 145.125 us; speedup vs baseline: 2.5676x; 1.0077x over previous
//
#include <hip/hip_runtime.h>

typedef short short8 __attribute__((ext_vector_type(8)));
typedef float f32x4 __attribute__((ext_vector_type(4)));
typedef unsigned short ushort;
typedef unsigned int uint;

#define MFMA16(a,b,c) __builtin_amdgcn_mfma_f32_16x16x32_bf16(a,b,c,0,0,0)
#define DPROJ 1552
#define LOG2E 1.44269504f

// ---- workspace byte offsets ----
constexpr size_t OFF_M    = 0;                         // 3*1552 f32
constexpr size_t OFF_CB_B = 0x5000;                    // 1552 f32
constexpr size_t OFF_WT   = 0x8000;                    // 128*512 bf16
constexpr size_t OFF_XT   = 0x30000;                   // [bc128][h16][grp16][p32][e8] u16 = 16 MB
constexpr size_t OFF_DT   = OFF_XT  + 16777216ull;     // 16384*16 f32
constexpr size_t OFF_BCM  = OFF_DT  + 1048576ull;      // [row][512] u16 (B|C)
constexpr size_t OFF_CUM  = OFF_BCM + 16777216ull;     // 2048*128 f32 (log2 units)
constexpr size_t OFF_CDC  = OFF_CUM + 1048576ull;      // 2048 f32
constexpr size_t OFF_CBT  = OFF_CDC + 8192ull;         // [bc][grp16][t128][e8] u16, PRE-MASKED
constexpr size_t OFF_BT   = OFF_CBT + 4194304ull;      // [bc][grp16][n256][e8] u16 = 8 MB
constexpr size_t OFF_ST   = OFF_BT  + 8388608ull;      // [bi][grp32][p32][e8] u16 = 32 MB
constexpr size_t OFF_Y    = OFF_ST  + 33554432ull;     // 16384*512 bf16

__device__ __forceinline__ float sigm(float x){ return 1.0f/(1.0f + __expf(-x)); }
__device__ __forceinline__ ushort f2bf(float f){
  union { float f; uint u; } c; c.f = f;
  uint u = c.u;
  return (ushort)((u + 0x7FFFu + ((u>>16)&1u)) >> 16);
}
__device__ __forceinline__ float bf2f(ushort h){
  union { uint u; float f; } c; c.u = ((uint)h)<<16;
  return c.f;
}
// XCD swizzle for 2048-block grids: all 16 heads of one (b,c) on one XCD
__device__ __forceinline__ void swz2048(int p, int& bc, int& h){
  int xcd = p & 7, slot = p >> 3;
  bc = xcd*16 + (slot >> 4);
  h  = slot & 15;
}

// ------- K0m: fuse fc0 into in_proj + WoutT'[d][i] = norm_w[i]*Wout[i][d] -------
__global__ __launch_bounds__(256) void k0m_prep(const float* __restrict__ fc0_w,
                                                const float* __restrict__ fc0_b,
                                                const float* __restrict__ W,
                                                const float* __restrict__ norm_w,
                                                const float* __restrict__ Wout,
                                                char* __restrict__ wsb){
  int d = blockIdx.x;                     // 128 blocks
  ushort* WT = (ushort*)(wsb + OFF_WT);
  for (int i = threadIdx.x; i < 512; i += 256)
    WT[(size_t)d*512 + i] = f2bf(norm_w[i]*Wout[(size_t)i*128 + d]);
  if (d < 7){
    int j = d*256 + threadIdx.x;
    if (j >= DPROJ) return;
    float* Mo = (float*)(wsb + OFF_M);
    float* Co = (float*)(wsb + OFF_CB_B);
    float m0=0.f,m1=0.f,m2=0.f,cc=0.f;
    for (int dd=0; dd<128; ++dd){
      float w = W[(size_t)dd*DPROJ + j];
      m0 = fmaf(fc0_w[dd],     w, m0);
      m1 = fmaf(fc0_w[128+dd], w, m1);
      m2 = fmaf(fc0_w[256+dd], w, m2);
      cc = fmaf(fc0_b[dd],     w, cc);
    }
    Mo[j] = m0; Mo[DPROJ + j] = m1; Mo[2*DPROJ + j] = m2;
    Co[j] = cc;
  }
}

// ------ K12: fused proj+causal conv(4)+silu -> xT tiled / BC row / BT tiled -----
__device__ __forceinline__ void proj8(int li, const float* __restrict__ xb,
                                      const float* m0, const float* m1, const float* m2,
                                      const float* c8, float* dst){
  if (li < 0){
    #pragma unroll
    for (int j=0;j<8;++j) dst[j] = 0.f;
    return;
  }
  int hh, wv;
  if (li < 4096){ hh = li>>6; wv = li&63; }
  else { int l2 = li-4096; hh = 63-(l2>>6); wv = 63-(l2&63); }
  float x0 = xb[hh*64+wv], x1 = xb[4096+hh*64+wv], x2 = xb[8192+hh*64+wv];
  #pragma unroll
  for (int j=0;j<8;++j)
    dst[j] = fmaf(x2, m2[j], fmaf(x1, m1[j], fmaf(x0, m0[j], c8[j])));
}

__device__ __forceinline__ void conv8(const float* cb8, const float* cw0, const float* cw1,
                                      const float* cw2, const float* cw3,
                                      const float* wA, const float* wB,
                                      const float* wC, const float* wD, ushort* o){
  #pragma unroll
  for (int j=0;j<8;++j){
    float a = cb8[j];
    a = fmaf(wA[j], cw0[j], a);
    a = fmaf(wB[j], cw1[j], a);
    a = fmaf(wC[j], cw2[j], a);
    a = fmaf(wD[j], cw3[j], a);
    o[j] = f2bf(a * sigm(a));
  }
}

__global__ __launch_bounds__(256) void k12_projconv(const float* __restrict__ x,
                                                    const float* __restrict__ conv_w,
                                                    const float* __restrict__ conv_b,
                                                    char* __restrict__ wsb){
  int tid = threadIdx.x;
  int cg = tid & 127, rl = tid >> 7;
  int row0 = blockIdx.x*16 + rl*8;        // 1024 blocks, 16 rows each
  int b = row0 >> 13, l0 = row0 & 8191;
  const float* M  = (const float*)(wsb + OFF_M);
  const float* Cc = (const float*)(wsb + OFF_CB_B);
  const float* xb = x + (size_t)b*12288;
  int ch0 = cg*8, j0 = 512 + ch0;
  float m0[8],m1[8],m2[8],c8[8],cw0[8],cw1[8],cw2[8],cw3[8],cb8[8];
  #pragma unroll
  for (int j=0;j<8;++j){
    m0[j]=M[j0+j]; m1[j]=M[DPROJ+j0+j]; m2[j]=M[2*DPROJ+j0+j]; c8[j]=Cc[j0+j];
    cw0[j]=conv_w[(ch0+j)*4+0]; cw1[j]=conv_w[(ch0+j)*4+1];
    cw2[j]=conv_w[(ch0+j)*4+2]; cw3[j]=conv_w[(ch0+j)*4+3];
    cb8[j]=conv_b[ch0+j];
  }
  bool is_xs = (ch0 < 512);
  bool is_b  = (ch0 >= 512) && (ch0 < 768);
  bool pack  = is_xs || is_b;
  ushort* bcmp = (ushort*)(wsb + OFF_BCM);
  int chb = ch0 - 512;
  uint colw[8][4];        // [ch j][row-pair] packed bf16x2, static idx only
  ushort oprev[8];
  float w0[8],w1[8],w2[8],w3[8];
  ushort o[8];
  proj8(l0-3, xb, m0,m1,m2,c8, w1);
  proj8(l0-2, xb, m0,m1,m2,c8, w2);
  proj8(l0-1, xb, m0,m1,m2,c8, w3);

#define ROW_EVEN(R, WN, WA, WB, WC)                                          \
  proj8(l0+R, xb, m0,m1,m2,c8, WN);                                          \
  conv8(cb8,cw0,cw1,cw2,cw3, WA,WB,WC,WN, o);                                \
  if (pack){ _Pragma("unroll")                                               \
    for (int j=0;j<8;++j) oprev[j] = o[j]; }                                 \
  if (!is_xs) *(uint4*)(bcmp + (size_t)(row0+R)*512 + chb) = *(uint4*)o;
#define ROW_ODD(R, WN, WA, WB, WC)                                           \
  proj8(l0+R, xb, m0,m1,m2,c8, WN);                                          \
  conv8(cb8,cw0,cw1,cw2,cw3, WA,WB,WC,WN, o);                                \
  if (pack){ _Pragma("unroll")                                               \
    for (int j=0;j<8;++j) colw[j][(R)>>1] = (uint)oprev[j] | ((uint)o[j]<<16); } \
  if (!is_xs) *(uint4*)(bcmp + (size_t)(row0+R)*512 + chb) = *(uint4*)o;

  ROW_EVEN(0, w0, w1,w2,w3)
  ROW_ODD (1, w1, w2,w3,w0)
  ROW_EVEN(2, w2, w3,w0,w1)
  ROW_ODD (3, w3, w0,w1,w2)
  ROW_EVEN(4, w0, w1,w2,w3)
  ROW_ODD (5, w1, w2,w3,w0)
  ROW_EVEN(6, w2, w3,w0,w1)
  ROW_ODD (7, w3, w0,w1,w2)
#undef ROW_EVEN
#undef ROW_ODD

  int bc = row0>>7, grp = (row0&127)>>3;
  if (is_xs){
    int h = ch0>>5, p0 = ch0&31;
    ushort* dst = (ushort*)(wsb+OFF_XT) + (((size_t)(bc*16+h)*16 + grp)*32)*8;
    #pragma unroll
    for (int j=0;j<8;++j){
      uint4 v; v.x = colw[j][0]; v.y = colw[j][1]; v.z = colw[j][2]; v.w = colw[j][3];
      *(uint4*)(dst + (size_t)(p0+j)*8) = v;
    }
  } else if (is_b){
    // BT tiled: [bc][grp16][n256][e8]
    ushort* btb = (ushort*)(wsb+OFF_BT) + (size_t)bc*32768;
    #pragma unroll
    for (int j=0;j<8;++j){
      uint4 v; v.x = colw[j][0]; v.y = colw[j][1]; v.z = colw[j][2]; v.w = colw[j][3];
      *(uint4*)(btb + (size_t)(grp*256 + chb + j)*8) = v;
    }
  }
}

// ------- K4a: CB = C·B^T via MFMA -> cbt tiled, PRE-MASKED (t<s -> 0) -----------
__global__ __launch_bounds__(256) void k4a_cb(char* __restrict__ wsb){
  int bi = blockIdx.x;                    // (b*64+c)*4 + squad
  int sq = bi & 3; int bc = bi >> 2;
  __shared__ __align__(16) char sC[16384];   // C[128][64] bf16 swizzled rows(128B)
  __shared__ __align__(16) char sB[4096];    // B[32][64]  bf16 swizzled
  const ushort* bcm = (const ushort*)(wsb + OFF_BCM);
  ushort* cbtT = (ushort*)(wsb + OFF_CBT) + (size_t)bc*16384;
  size_t rb = (size_t)bc*128;
  int tid = threadIdx.x;
  int lane = tid&63, wid = tid>>6, l15 = lane&15, l4 = lane>>4;
  int s_base = sq*32;
  f32x4 acc[2][2] = {};
  for (int nt = 0; nt < 4; ++nt){
    int n0 = nt*64;
    __syncthreads();
    for (int idx = tid; idx < 1024; idx += 256){
      int t = idx>>3, c = idx&7;
      uint4 v = *(const uint4*)(bcm + (rb+t)*512 + 256 + n0 + c*8);
      *(uint4*)(sC + ((t*128 + c*16) ^ ((t&7)<<4))) = v;
    }
    {
      int idx = tid;
      int s = idx>>3, c = idx&7;
      uint4 v = *(const uint4*)(bcm + (rb+s_base+s)*512 + n0 + c*8);
      *(uint4*)(sB + ((s*128 + c*16) ^ ((s&7)<<4))) = v;
    }
    __syncthreads();
    if (wid >= sq){   // triangle trim
      #pragma unroll
      for (int ks = 0; ks < 2; ++ks){
        int kb = ks*64 + l4*16;
        int t0 = wid*32 + l15, t1 = t0 + 16;
        short8 a0 = *(const short8*)(sC + ((t0*128 + kb) ^ ((t0&7)<<4)));
        short8 a1 = *(const short8*)(sC + ((t1*128 + kb) ^ ((t1&7)<<4)));
        short8 b0 = *(const short8*)(sB + ((l15*128 + kb) ^ ((l15&7)<<4)));
        short8 b1 = *(const short8*)(sB + (((16+l15)*128 + kb) ^ (((16+l15)&7)<<4)));
        acc[0][0] = MFMA16(a0,b0,acc[0][0]);
        acc[0][1] = MFMA16(a0,b1,acc[0][1]);
        acc[1][0] = MFMA16(a1,b0,acc[1][0]);
        acc[1][1] = MFMA16(a1,b1,acc[1][1]);
      }
    }
  }
  #pragma unroll
  for (int mt=0; mt<2; ++mt)
  #pragma unroll
  for (int st=0; st<2; ++st)
  #pragma unroll
  for (int r=0; r<4; ++r){
    int t = wid*32 + mt*16 + l4*4 + r;
    int s = s_base + st*16 + l15;
    float v = (t >= s) ? acc[mt][st][r] : 0.f;   // pre-mask upper triangle
    cbtT[(size_t)((s>>3)*128 + t)*8 + (s&7)] = f2bf(v);
  }
}

// -- K4sc: dt-proj + cumsum + states = (x*w)^T @ B -------------------------------
__global__ __launch_bounds__(256) void k4sc_states(const float* __restrict__ x,
                                                   const float* __restrict__ dt_bias,
                                                   const float* __restrict__ A_log,
                                                   char* __restrict__ wsb){
  int bc, h; swz2048(blockIdx.x, bc, h);
  int bi = bc*16 + h;
  __shared__ float sCS[128];
  __shared__ float sW[128];
  const ushort* xt  = (const ushort*)(wsb + OFF_XT) + (size_t)bi*4096;
  const ushort* btb = (const ushort*)(wsb + OFF_BT) + (size_t)bc*32768;
  ushort* st = (ushort*)(wsb + OFF_ST) + (size_t)bi*8192;
  int tid = threadIdx.x;
  float dtv = 0.f;
  if (tid < 128){
    int r = bc*128 + tid;
    int b = r >> 13, l = r & 8191;
    int hp, wv;
    if (l < 4096){ hp = l>>6; wv = l&63; }
    else { int l2 = l-4096; hp = 63-(l2>>6); wv = 63-(l2&63); }
    const float* xb = x + (size_t)b*12288;
    float x0 = xb[hp*64+wv], x1 = xb[4096+hp*64+wv], x2 = xb[8192+hp*64+wv];
    const float* M  = (const float*)(wsb + OFF_M);
    const float* Cc = (const float*)(wsb + OFF_CB_B);
    int j = 1536 + h;
    float v = Cc[j];
    v = fmaf(x0, M[j], v);
    v = fmaf(x1, M[DPROJ+j], v);
    v = fmaf(x2, M[2*DPROJ+j], v);
    float tt = v + dt_bias[h];
    dtv = (tt > 20.f) ? tt : log1pf(__expf(tt));
    ((float*)(wsb+OFF_DT))[(size_t)r*16 + h] = dtv;
    float A2 = -__expf(A_log[h]) * LOG2E;
    sCS[tid] = dtv * A2;
  }
  __syncthreads();
  for (int off=1; off<128; off<<=1){
    float sv = (tid>=off && tid<128) ? sCS[tid-off] : 0.f;
    __syncthreads();
    if (tid < 128) sCS[tid] += sv;
    __syncthreads();
  }
  if (tid < 128){
    float cv = sCS[tid];
    ((float*)(wsb + OFF_CUM))[(size_t)bi*128 + tid] = cv;
    if (tid == 127) ((float*)(wsb + OFF_CDC))[bi] = exp2f(cv);
  }
  __syncthreads();
  if (tid < 128) sW[tid] = exp2f(sCS[127] - sCS[tid]) * dtv;
  __syncthreads();
  int lane = tid&63, wid = tid>>6, l15 = lane&15, l4 = lane>>4;
  f32x4 acc2[2][4] = {};
  #pragma unroll
  for (int ks = 0; ks < 4; ++ks){
    int grp = ks*4 + l4;
    const float* wp = sW + grp*8;
    short8 ra0 = *(const short8*)(xt + (size_t)(grp*32 + l15)*8);
    short8 ra1 = *(const short8*)(xt + (size_t)(grp*32 + 16 + l15)*8);
    short8 a0, a1;
    #pragma unroll
    for (int j=0;j<8;++j){
      a0[j] = (short)f2bf(bf2f((ushort)ra0[j]) * wp[j]);
      a1[j] = (short)f2bf(bf2f((ushort)ra1[j]) * wp[j]);
    }
    #pragma unroll
    for (int ntl = 0; ntl < 4; ++ntl){
      int n = wid*64 + ntl*16 + l15;
      short8 b = *(const short8*)(btb + (size_t)(grp*256 + n)*8);
      acc2[0][ntl] = MFMA16(a0,b,acc2[0][ntl]);
      acc2[1][ntl] = MFMA16(a1,b,acc2[1][ntl]);
    }
  }
  #pragma unroll
  for (int mt=0; mt<2; ++mt)
  #pragma unroll
  for (int ntl=0; ntl<4; ++ntl)
  #pragma unroll
  for (int r=0; r<4; ++r){
    int p = mt*16 + l4*4 + r;
    int n = wid*64 + ntl*16 + l15;
    st[(size_t)((n>>3)*32 + p)*8 + (n&7)] = f2bf(acc2[mt][ntl][r]);
  }
}

// ---------------- K5: sequential chunk scan, pack-2 (uint per thread) -----------
__global__ __launch_bounds__(256) void k5_scan(char* __restrict__ wsb){
  int g = blockIdx.x*256 + threadIdx.x;   // 131072 threads (512 blocks)
  int idx32 = g*2;
  int e = idx32 & 7;
  int q = idx32 >> 3;
  int p = q & 31; q >>= 5;
  int grp = q & 31; q >>= 5;
  int h = q & 15; int b = q >> 4;
  int off32 = (grp*32 + p)*4 + (e>>1);
  uint* st32 = (uint*)(wsb + OFF_ST);
  const float* cdc = (const float*)(wsb + OFF_CDC);
  float S0 = 0.f, S1 = 0.f;
  for (int c=0; c<64; ++c){
    int bi = (b*64+c)*16 + h;
    size_t idx = (size_t)bi*4096 + off32;
    uint v = st32[idx];
    float v0 = bf2f((ushort)(v & 0xFFFFu));
    float v1 = bf2f((ushort)(v >> 16));
    st32[idx] = (uint)f2bf(S0) | ((uint)f2bf(S1) << 16);
    float cd = cdc[bi];
    S0 = fmaf(S0, cd, v0);
    S1 = fmaf(S1, cd, v1);
  }
}

// -------- K4y: y = attn@x + exp2(cum)*C@prev + D*x -> Y bf16 (LDS-staged) -------
__global__ __launch_bounds__(256) void k4y_out(const float* __restrict__ Dp,
                                               char* __restrict__ wsb){
  int bc, h; swz2048(blockIdx.x, bc, h);
  int bi = bc*16 + h;
  __shared__ float sCum[128], sDt[128], sE[128];
  __shared__ __align__(16) char sPrev[16384];   // [grp32][p32][e8] bf16, linear
  __shared__ __align__(16) char sXT[8192];      // [grp16][p32][e8] bf16, linear
  const ushort* cbt = (const ushort*)(wsb + OFF_CBT) + (size_t)bc*16384;
  const char* xtg   = (const char*)(wsb + OFF_XT) + (size_t)bi*8192;
  const char* prevg = (const char*)(wsb + OFF_ST) + (size_t)bi*16384;
  const ushort* bcm = (const ushort*)(wsb + OFF_BCM);
  const float* cum  = (const float*)(wsb + OFF_CUM) + (size_t)bi*128;
  const float* dtp  = (const float*)(wsb + OFF_DT);
  ushort* Yb = (ushort*)(wsb + OFF_Y);
  size_t rb = (size_t)bc*128;
  int tid = threadIdx.x;
  // stage prev (16KB) + xt (8KB) once per block, vectorized
  #pragma unroll
  for (int i=0;i<4;++i)
    *(uint4*)(sPrev + i*4096 + tid*16) = *(const uint4*)(prevg + (size_t)i*4096 + tid*16);
  #pragma unroll
  for (int i=0;i<2;++i)
    *(uint4*)(sXT + i*4096 + tid*16) = *(const uint4*)(xtg + (size_t)i*4096 + tid*16);
  if (tid < 128){
    float cv = cum[tid];
    sCum[tid] = cv;
    sDt[tid]  = dtp[(rb+tid)*16 + h];
    sE[tid]   = exp2f(cv);
  }
  __syncthreads();
  int lane = tid&63, wid = tid>>6, l15 = lane&15, l4 = lane>>4;
  int t0 = wid*32 + l15, t1 = t0 + 16;
  float ct0 = sCum[t0], ct1 = sCum[t1];
  // ---- y_intra: A = CBmask*decay*dt in-register; triangle-trimmed ks loop ----
  f32x4 acc[2][2] = {};
  #pragma unroll
  for (int ks = 0; ks < 4; ++ks){
    if (ks <= wid){
      int grp = ks*4 + l4;
      int s0 = grp*8;
      short8 ra0 = *(const short8*)(cbt + (size_t)(grp*128 + t0)*8);
      short8 ra1 = *(const short8*)(cbt + (size_t)(grp*128 + t1)*8);
      short8 a0, a1;
      #pragma unroll
      for (int j=0;j<8;++j){
        int s = s0 + j;
        float cs = sCum[s], ds = sDt[s];
        float e0 = exp2f(fminf(ct0 - cs, 0.f)) * ds;   // clamp mandatory: 0*inf=NaN
        float e1 = exp2f(fminf(ct1 - cs, 0.f)) * ds;
        a0[j] = (short)f2bf(bf2f((ushort)ra0[j]) * e0);  // CBT pre-masked
        a1[j] = (short)f2bf(bf2f((ushort)ra1[j]) * e1);
      }
      short8 b0 = *(const short8*)(sXT + (grp*32 + l15)*16);
      short8 b1 = *(const short8*)(sXT + (grp*32 + 16 + l15)*16);
      acc[0][0] = MFMA16(a0,b0,acc[0][0]);
      acc[0][1] = MFMA16(a0,b1,acc[0][1]);
      acc[1][0] = MFMA16(a1,b0,acc[1][0]);
      acc[1][1] = MFMA16(a1,b1,acc[1][1]);
    }
  }
  // ---- y_inter = C @ prev^T : K=n(256), prev from LDS ----
  f32x4 acc2[2][2] = {};
  #pragma unroll
  for (int ks = 0; ks < 8; ++ks){
    int koff = ks*32 + l4*8;
    int grp = ks*4 + l4;
    short8 a0 = *(const short8*)(bcm + (rb+t0)*512 + 256 + koff);
    short8 a1 = *(const short8*)(bcm + (rb+t1)*512 + 256 + koff);
    short8 b0 = *(const short8*)(sPrev + (grp*32 + l15)*16);
    short8 b1 = *(const short8*)(sPrev + (grp*32 + 16 + l15)*16);
    acc2[0][0] = MFMA16(a0,b0,acc2[0][0]);
    acc2[0][1] = MFMA16(a0,b1,acc2[0][1]);
    acc2[1][0] = MFMA16(a1,b0,acc2[1][0]);
    acc2[1][1] = MFMA16(a1,b1,acc2[1][1]);
  }
  float Dh = Dp[h];
  #pragma unroll
  for (int mt=0; mt<2; ++mt){
    int tb = wid*32 + mt*16 + l4*4;
    int tg = tb>>3, e0i = tb&7;
    #pragma unroll
    for (int nt=0; nt<2; ++nt){
      int p = nt*16 + l15;
      ushort xv[4];
      *(uint2*)xv = *(const uint2*)(sXT + ((tg*32 + p)*8 + e0i)*2);
      #pragma unroll
      for (int r=0; r<4; ++r){
        int t = tb + r;
        float yv = acc[mt][nt][r] + sE[t]*acc2[mt][nt][r] + Dh*bf2f(xv[r]);
        Yb[(rb+t)*512 + h*32 + p] = f2bf(yv);
      }
    }
  }
}

// ---------------- K7: gate(silu(z)) -> RMS -> out_proj (MFMA) -------------------
__global__ __launch_bounds__(256) void k7_final(const float* __restrict__ x,
                                                char* __restrict__ wsb,
                                                float* __restrict__ out){
  int r0 = blockIdx.x*32;                  // 512 blocks
  __shared__ __align__(16) char sG[32768]; // G[32][512] bf16 rows 1024B, swizzled
  __shared__ float sScale[32];
  const ushort* Yb = (const ushort*)(wsb + OFF_Y);
  const float* M  = (const float*)(wsb + OFF_M);
  const float* Cb = (const float*)(wsb + OFF_CB_B);
  const ushort* WT = (const ushort*)(wsb + OFF_WT);
  int tid = threadIdx.x;
  int r = tid>>3, li = tid&7;
  int row = r0 + r; int b = row>>13, l = row & 8191;
  int hh, wv;
  if (l < 4096){ hh = l>>6; wv = l&63; }
  else { int l2 = l-4096; hh = 63-(l2>>6); wv = 63-(l2&63); }
  const float* xb = x + (size_t)b*12288;
  float x0 = xb[hh*64+wv], x1 = xb[4096+hh*64+wv], x2 = xb[8192+hh*64+wv];
  float sq = 0.f;
  #pragma unroll
  for (int k = 0; k < 8; ++k){
    int i0 = li*64 + k*8;
    short8 yv = *(const short8*)(Yb + (size_t)row*512 + i0);
    ushort g8[8];
    #pragma unroll
    for (int j=0;j<8;++j){
      int i = i0 + j;
      float z = Cb[i];
      z = fmaf(x0, M[i], z);
      z = fmaf(x1, M[DPROJ+i], z);
      z = fmaf(x2, M[2*DPROJ+i], z);
      float g = bf2f((ushort)yv[j]) * z * sigm(z);
      sq = fmaf(g, g, sq);
      g8[j] = f2bf(g);
    }
    *(uint4*)(sG + ((r*1024 + i0*2) ^ ((r&7)<<4))) = *(uint4*)g8;
  }
  sq += __shfl_xor(sq, 1, 64);
  sq += __shfl_xor(sq, 2, 64);
  sq += __shfl_xor(sq, 4, 64);
  if (li == 0) sScale[r] = rsqrtf(sq*(1.f/512.f) + 1e-5f);
  __syncthreads();
  int lane = tid&63, wid = tid>>6, l15 = lane&15, l4 = lane>>4;
  f32x4 acc[2][2] = {};
  #pragma unroll
  for (int ks = 0; ks < 16; ++ks){
    int kb = ks*64 + l4*16;
    int rr0 = l15, rr1 = 16+l15;
    short8 a0 = *(const short8*)(sG + ((rr0*1024 + kb) ^ ((rr0&7)<<4)));
    short8 a1 = *(const short8*)(sG + ((rr1*1024 + kb) ^ ((rr1&7)<<4)));
    int koff = ks*32 + l4*8;
    short8 b0 = *(const short8*)(WT + (size_t)(wid*32 + l15)*512 + koff);
    short8 b1 = *(const short8*)(WT + (size_t)(wid*32 + 16 + l15)*512 + koff);
    acc[0][0] = MFMA16(a0,b0,acc[0][0]);
    acc[0][1] = MFMA16(a0,b1,acc[0][1]);
    acc[1][0] = MFMA16(a1,b0,acc[1][0]);
    acc[1][1] = MFMA16(a1,b1,acc[1][1]);
  }
  #pragma unroll
  for (int mt=0; mt<2; ++mt)
  #pragma unroll
  for (int nt=0; nt<2; ++nt)
  #pragma unroll
  for (int r4=0; r4<4; ++r4){
    int rr = mt*16 + l4*4 + r4;
    int d = wid*32 + nt*16 + l15;
    out[(size_t)(r0+rr)*128 + d] = acc[mt][nt][r4] * sScale[rr];
  }
}

extern "C" void kernel_launch(void* const* d_in, const int* in_sizes, int n_in,
                              void* d_out, int out_size, void* d_ws, size_t ws_size,
                              hipStream_t stream) {
  const float* x         = (const float*)d_in[0];
  const float* fc0_w     = (const float*)d_in[1];
  const float* fc0_b     = (const float*)d_in[2];
  const float* in_proj_w = (const float*)d_in[3];
  const float* conv_w    = (const float*)d_in[4];
  const float* conv_b    = (const float*)d_in[5];
  const float* dt_bias   = (const float*)d_in[6];
  const float* A_log     = (const float*)d_in[7];
  const float* Dp        = (const float*)d_in[8];
  const float* norm_w    = (const float*)d_in[9];
  const float* out_proj_w= (const float*)d_in[10];
  char* wsb  = (char*)d_ws;
  float* out = (float*)d_out;

  k0m_prep<<<dim3(128),  dim3(256), 0, stream>>>(fc0_w, fc0_b, in_proj_w, norm_w, out_proj_w, wsb);
  k12_projconv<<<dim3(1024), dim3(256), 0, stream>>>(x, conv_w, conv_b, wsb);
  k4a_cb <<<dim3(512),   dim3(256), 0, stream>>>(wsb);
  k4sc_states<<<dim3(2048), dim3(256), 0, stream>>>(x, dt_bias, A_log, wsb);
  k5_scan<<<dim3(512),   dim3(256), 0, stream>>>(wsb);
  k4y_out<<<dim3(2048),  dim3(256), 0, stream>>>(Dp, wsb);
  k7_final<<<dim3(512),  dim3(256), 0, stream>>>(x, wsb, out);
}

// Round 11
// 138.426 us; speedup vs baseline: 2.6919x; 1.0484x over previous
//
#include <hip/hip_runtime.h>
#include <hip/hip_bf16.h>

typedef short short8 __attribute__((ext_vector_type(8)));
typedef float f32x4 __attribute__((ext_vector_type(4)));
typedef unsigned short ushort;
typedef unsigned int uint;

#define MFMA16(a,b,c) __builtin_amdgcn_mfma_f32_16x16x32_bf16(a,b,c,0,0,0)
#define DPROJ 1552
#define LOG2E 1.44269504f

// ---- workspace byte offsets ----
constexpr size_t OFF_M    = 0;                         // 3*1552 f32
constexpr size_t OFF_CB_B = 0x5000;                    // 1552 f32
constexpr size_t OFF_WT   = 0x8000;                    // 128*512 bf16
constexpr size_t OFF_XT   = 0x30000;                   // [bc128][h16][grp16][p32][e8] u16 = 16 MB
constexpr size_t OFF_DT   = OFF_XT  + 16777216ull;     // 16384*16 f32
constexpr size_t OFF_BCM  = OFF_DT  + 1048576ull;      // [row][512] u16 (B|C)
constexpr size_t OFF_CUM  = OFF_BCM + 16777216ull;     // 2048*128 f32 (log2 units)
constexpr size_t OFF_CDC  = OFF_CUM + 1048576ull;      // 2048 f32
constexpr size_t OFF_CBT  = OFF_CDC + 8192ull;         // [bc][grp16][t128][e8] u16, PRE-MASKED
constexpr size_t OFF_BT   = OFF_CBT + 4194304ull;      // [bc][grp16][n256][e8] u16 = 8 MB
constexpr size_t OFF_ST   = OFF_BT  + 8388608ull;      // [bi][grp32][p32][e8] u16 = 32 MB
constexpr size_t OFF_Y    = OFF_ST  + 33554432ull;     // 16384*512 bf16

__device__ __forceinline__ float sigm(float x){ return 1.0f/(1.0f + __expf(-x)); }
// HW bf16 convert (RTNE) — lets the compiler fuse pairs into v_cvt_pk_bf16_f32
__device__ __forceinline__ ushort f2bf(float f){
  union { __hip_bfloat16 h; ushort u; } c;
  c.h = __float2bfloat16(f);
  return c.u;
}
__device__ __forceinline__ float bf2f(ushort h){
  union { uint u; float f; } c; c.u = ((uint)h)<<16;
  return c.f;
}
// XCD swizzle for 2048-block grids: all 16 heads of one (b,c) on one XCD
__device__ __forceinline__ void swz2048(int p, int& bc, int& h){
  int xcd = p & 7, slot = p >> 3;
  bc = xcd*16 + (slot >> 4);
  h  = slot & 15;
}

// ------- K0m: fuse fc0 into in_proj + WoutT'[d][i] = norm_w[i]*Wout[i][d] -------
__global__ __launch_bounds__(256) void k0m_prep(const float* __restrict__ fc0_w,
                                                const float* __restrict__ fc0_b,
                                                const float* __restrict__ W,
                                                const float* __restrict__ norm_w,
                                                const float* __restrict__ Wout,
                                                char* __restrict__ wsb){
  int d = blockIdx.x;                     // 128 blocks
  ushort* WT = (ushort*)(wsb + OFF_WT);
  for (int i = threadIdx.x; i < 512; i += 256)
    WT[(size_t)d*512 + i] = f2bf(norm_w[i]*Wout[(size_t)i*128 + d]);
  if (d < 7){
    int j = d*256 + threadIdx.x;
    if (j >= DPROJ) return;
    float* Mo = (float*)(wsb + OFF_M);
    float* Co = (float*)(wsb + OFF_CB_B);
    float m0=0.f,m1=0.f,m2=0.f,cc=0.f;
    for (int dd=0; dd<128; ++dd){
      float w = W[(size_t)dd*DPROJ + j];
      m0 = fmaf(fc0_w[dd],     w, m0);
      m1 = fmaf(fc0_w[128+dd], w, m1);
      m2 = fmaf(fc0_w[256+dd], w, m2);
      cc = fmaf(fc0_b[dd],     w, cc);
    }
    Mo[j] = m0; Mo[DPROJ + j] = m1; Mo[2*DPROJ + j] = m2;
    Co[j] = cc;
  }
}

// ------ K12: fused proj+causal conv(4)+silu -> xT tiled / BC row / BT tiled -----
__device__ __forceinline__ void proj8(int li, const float* __restrict__ xb,
                                      const float* m0, const float* m1, const float* m2,
                                      const float* c8, float* dst){
  if (li < 0){
    #pragma unroll
    for (int j=0;j<8;++j) dst[j] = 0.f;
    return;
  }
  int hh, wv;
  if (li < 4096){ hh = li>>6; wv = li&63; }
  else { int l2 = li-4096; hh = 63-(l2>>6); wv = 63-(l2&63); }
  float x0 = xb[hh*64+wv], x1 = xb[4096+hh*64+wv], x2 = xb[8192+hh*64+wv];
  #pragma unroll
  for (int j=0;j<8;++j)
    dst[j] = fmaf(x2, m2[j], fmaf(x1, m1[j], fmaf(x0, m0[j], c8[j])));
}

__device__ __forceinline__ void conv8(const float* cb8, const float* cw0, const float* cw1,
                                      const float* cw2, const float* cw3,
                                      const float* wA, const float* wB,
                                      const float* wC, const float* wD, ushort* o){
  #pragma unroll
  for (int j=0;j<8;++j){
    float a = cb8[j];
    a = fmaf(wA[j], cw0[j], a);
    a = fmaf(wB[j], cw1[j], a);
    a = fmaf(wC[j], cw2[j], a);
    a = fmaf(wD[j], cw3[j], a);
    o[j] = f2bf(a * sigm(a));
  }
}

__global__ __launch_bounds__(256) void k12_projconv(const float* __restrict__ x,
                                                    const float* __restrict__ conv_w,
                                                    const float* __restrict__ conv_b,
                                                    char* __restrict__ wsb){
  int tid = threadIdx.x;
  int cg = tid & 127, rl = tid >> 7;
  int row0 = blockIdx.x*16 + rl*8;        // 1024 blocks, 16 rows each
  int b = row0 >> 13, l0 = row0 & 8191;
  const float* M  = (const float*)(wsb + OFF_M);
  const float* Cc = (const float*)(wsb + OFF_CB_B);
  const float* xb = x + (size_t)b*12288;
  int ch0 = cg*8, j0 = 512 + ch0;
  float m0[8],m1[8],m2[8],c8[8],cw0[8],cw1[8],cw2[8],cw3[8],cb8[8];
  #pragma unroll
  for (int j=0;j<8;++j){
    m0[j]=M[j0+j]; m1[j]=M[DPROJ+j0+j]; m2[j]=M[2*DPROJ+j0+j]; c8[j]=Cc[j0+j];
    cw0[j]=conv_w[(ch0+j)*4+0]; cw1[j]=conv_w[(ch0+j)*4+1];
    cw2[j]=conv_w[(ch0+j)*4+2]; cw3[j]=conv_w[(ch0+j)*4+3];
    cb8[j]=conv_b[ch0+j];
  }
  bool is_xs = (ch0 < 512);
  bool is_b  = (ch0 >= 512) && (ch0 < 768);
  bool pack  = is_xs || is_b;
  ushort* bcmp = (ushort*)(wsb + OFF_BCM);
  int chb = ch0 - 512;
  uint colw[8][4];        // [ch j][row-pair] packed bf16x2, static idx only
  ushort oprev[8];
  float w0[8],w1[8],w2[8],w3[8];
  ushort o[8];
  proj8(l0-3, xb, m0,m1,m2,c8, w1);
  proj8(l0-2, xb, m0,m1,m2,c8, w2);
  proj8(l0-1, xb, m0,m1,m2,c8, w3);

#define ROW_EVEN(R, WN, WA, WB, WC)                                          \
  proj8(l0+R, xb, m0,m1,m2,c8, WN);                                          \
  conv8(cb8,cw0,cw1,cw2,cw3, WA,WB,WC,WN, o);                                \
  if (pack){ _Pragma("unroll")                                               \
    for (int j=0;j<8;++j) oprev[j] = o[j]; }                                 \
  if (!is_xs) *(uint4*)(bcmp + (size_t)(row0+R)*512 + chb) = *(uint4*)o;
#define ROW_ODD(R, WN, WA, WB, WC)                                           \
  proj8(l0+R, xb, m0,m1,m2,c8, WN);                                          \
  conv8(cb8,cw0,cw1,cw2,cw3, WA,WB,WC,WN, o);                                \
  if (pack){ _Pragma("unroll")                                               \
    for (int j=0;j<8;++j) colw[j][(R)>>1] = (uint)oprev[j] | ((uint)o[j]<<16); } \
  if (!is_xs) *(uint4*)(bcmp + (size_t)(row0+R)*512 + chb) = *(uint4*)o;

  ROW_EVEN(0, w0, w1,w2,w3)
  ROW_ODD (1, w1, w2,w3,w0)
  ROW_EVEN(2, w2, w3,w0,w1)
  ROW_ODD (3, w3, w0,w1,w2)
  ROW_EVEN(4, w0, w1,w2,w3)
  ROW_ODD (5, w1, w2,w3,w0)
  ROW_EVEN(6, w2, w3,w0,w1)
  ROW_ODD (7, w3, w0,w1,w2)
#undef ROW_EVEN
#undef ROW_ODD

  int bc = row0>>7, grp = (row0&127)>>3;
  if (is_xs){
    int h = ch0>>5, p0 = ch0&31;
    ushort* dst = (ushort*)(wsb+OFF_XT) + (((size_t)(bc*16+h)*16 + grp)*32)*8;
    #pragma unroll
    for (int j=0;j<8;++j){
      uint4 v; v.x = colw[j][0]; v.y = colw[j][1]; v.z = colw[j][2]; v.w = colw[j][3];
      *(uint4*)(dst + (size_t)(p0+j)*8) = v;
    }
  } else if (is_b){
    // BT tiled: [bc][grp16][n256][e8]
    ushort* btb = (ushort*)(wsb+OFF_BT) + (size_t)bc*32768;
    #pragma unroll
    for (int j=0;j<8;++j){
      uint4 v; v.x = colw[j][0]; v.y = colw[j][1]; v.z = colw[j][2]; v.w = colw[j][3];
      *(uint4*)(btb + (size_t)(grp*256 + chb + j)*8) = v;
    }
  }
}

// ---- K4m: merged {k4sc: dt-proj+cumsum+states} / {k4a: CB MFMA, pre-masked} ----
// blocks 0..2047 -> k4sc path; 2048..2559 -> k4a path. Both depend only on k12.
__global__ __launch_bounds__(256) void k4m(const float* __restrict__ x,
                                           const float* __restrict__ dt_bias,
                                           const float* __restrict__ A_log,
                                           char* __restrict__ wsb){
  __shared__ __align__(16) char sMem[20480];   // k4a: sC(16K)+sB(4K); k4sc: sCS/sW (1K)
  int tid = threadIdx.x;
  int lane = tid&63, wid = tid>>6, l15 = lane&15, l4 = lane>>4;

  if (blockIdx.x < 2048){
    // ================= k4sc path =================
    int bc, h; swz2048(blockIdx.x, bc, h);
    int bi = bc*16 + h;
    float* sCS = (float*)sMem;
    float* sW  = (float*)(sMem + 512);
    const ushort* xt  = (const ushort*)(wsb + OFF_XT) + (size_t)bi*4096;
    const ushort* btb = (const ushort*)(wsb + OFF_BT) + (size_t)bc*32768;
    ushort* st = (ushort*)(wsb + OFF_ST) + (size_t)bi*8192;
    float dtv = 0.f;
    if (tid < 128){
      int r = bc*128 + tid;
      int b = r >> 13, l = r & 8191;
      int hp, wv;
      if (l < 4096){ hp = l>>6; wv = l&63; }
      else { int l2 = l-4096; hp = 63-(l2>>6); wv = 63-(l2&63); }
      const float* xb = x + (size_t)b*12288;
      float x0 = xb[hp*64+wv], x1 = xb[4096+hp*64+wv], x2 = xb[8192+hp*64+wv];
      const float* M  = (const float*)(wsb + OFF_M);
      const float* Cc = (const float*)(wsb + OFF_CB_B);
      int j = 1536 + h;
      float v = Cc[j];
      v = fmaf(x0, M[j], v);
      v = fmaf(x1, M[DPROJ+j], v);
      v = fmaf(x2, M[2*DPROJ+j], v);
      float tt = v + dt_bias[h];
      dtv = (tt > 20.f) ? tt : log1pf(__expf(tt));
      ((float*)(wsb+OFF_DT))[(size_t)r*16 + h] = dtv;
      float A2 = -__expf(A_log[h]) * LOG2E;
      sCS[tid] = dtv * A2;
    }
    __syncthreads();
    for (int off=1; off<128; off<<=1){
      float sv = (tid>=off && tid<128) ? sCS[tid-off] : 0.f;
      __syncthreads();
      if (tid < 128) sCS[tid] += sv;
      __syncthreads();
    }
    if (tid < 128){
      float cv = sCS[tid];
      ((float*)(wsb + OFF_CUM))[(size_t)bi*128 + tid] = cv;
      if (tid == 127) ((float*)(wsb + OFF_CDC))[bi] = exp2f(cv);
    }
    __syncthreads();
    if (tid < 128) sW[tid] = exp2f(sCS[127] - sCS[tid]) * dtv;
    __syncthreads();
    f32x4 acc2[2][4] = {};
    #pragma unroll
    for (int ks = 0; ks < 4; ++ks){
      int grp = ks*4 + l4;
      const float* wp = sW + grp*8;
      short8 ra0 = *(const short8*)(xt + (size_t)(grp*32 + l15)*8);
      short8 ra1 = *(const short8*)(xt + (size_t)(grp*32 + 16 + l15)*8);
      short8 a0, a1;
      #pragma unroll
      for (int j=0;j<8;++j){
        a0[j] = (short)f2bf(bf2f((ushort)ra0[j]) * wp[j]);
        a1[j] = (short)f2bf(bf2f((ushort)ra1[j]) * wp[j]);
      }
      #pragma unroll
      for (int ntl = 0; ntl < 4; ++ntl){
        int n = wid*64 + ntl*16 + l15;
        short8 b = *(const short8*)(btb + (size_t)(grp*256 + n)*8);
        acc2[0][ntl] = MFMA16(a0,b,acc2[0][ntl]);
        acc2[1][ntl] = MFMA16(a1,b,acc2[1][ntl]);
      }
    }
    #pragma unroll
    for (int mt=0; mt<2; ++mt)
    #pragma unroll
    for (int ntl=0; ntl<4; ++ntl)
    #pragma unroll
    for (int r=0; r<4; ++r){
      int p = mt*16 + l4*4 + r;
      int n = wid*64 + ntl*16 + l15;
      st[(size_t)((n>>3)*32 + p)*8 + (n&7)] = f2bf(acc2[mt][ntl][r]);
    }
  } else {
    // ================= k4a path =================
    int bi = blockIdx.x - 2048;           // (b*64+c)*4 + squad
    int sq = bi & 3; int bc = bi >> 2;
    char* sC = sMem;                       // C[128][64] bf16 swizzled rows(128B)
    char* sB = sMem + 16384;               // B[32][64]  bf16 swizzled
    const ushort* bcm = (const ushort*)(wsb + OFF_BCM);
    ushort* cbtT = (ushort*)(wsb + OFF_CBT) + (size_t)bc*16384;
    size_t rb = (size_t)bc*128;
    int s_base = sq*32;
    f32x4 acc[2][2] = {};
    for (int nt = 0; nt < 4; ++nt){
      int n0 = nt*64;
      __syncthreads();
      for (int idx = tid; idx < 1024; idx += 256){
        int t = idx>>3, c = idx&7;
        uint4 v = *(const uint4*)(bcm + (rb+t)*512 + 256 + n0 + c*8);
        *(uint4*)(sC + ((t*128 + c*16) ^ ((t&7)<<4))) = v;
      }
      {
        int idx = tid;
        int s = idx>>3, c = idx&7;
        uint4 v = *(const uint4*)(bcm + (rb+s_base+s)*512 + n0 + c*8);
        *(uint4*)(sB + ((s*128 + c*16) ^ ((s&7)<<4))) = v;
      }
      __syncthreads();
      if (wid >= sq){   // triangle trim
        #pragma unroll
        for (int ks = 0; ks < 2; ++ks){
          int kb = ks*64 + l4*16;
          int t0 = wid*32 + l15, t1 = t0 + 16;
          short8 a0 = *(const short8*)(sC + ((t0*128 + kb) ^ ((t0&7)<<4)));
          short8 a1 = *(const short8*)(sC + ((t1*128 + kb) ^ ((t1&7)<<4)));
          short8 b0 = *(const short8*)(sB + ((l15*128 + kb) ^ ((l15&7)<<4)));
          short8 b1 = *(const short8*)(sB + (((16+l15)*128 + kb) ^ (((16+l15)&7)<<4)));
          acc[0][0] = MFMA16(a0,b0,acc[0][0]);
          acc[0][1] = MFMA16(a0,b1,acc[0][1]);
          acc[1][0] = MFMA16(a1,b0,acc[1][0]);
          acc[1][1] = MFMA16(a1,b1,acc[1][1]);
        }
      }
    }
    #pragma unroll
    for (int mt=0; mt<2; ++mt)
    #pragma unroll
    for (int st=0; st<2; ++st)
    #pragma unroll
    for (int r=0; r<4; ++r){
      int t = wid*32 + mt*16 + l4*4 + r;
      int s = s_base + st*16 + l15;
      float v = (t >= s) ? acc[mt][st][r] : 0.f;   // pre-mask upper triangle
      cbtT[(size_t)((s>>3)*128 + t)*8 + (s&7)] = f2bf(v);
    }
  }
}

// ---------------- K5: sequential chunk scan, pack-2 (uint per thread) -----------
__global__ __launch_bounds__(256) void k5_scan(char* __restrict__ wsb){
  int g = blockIdx.x*256 + threadIdx.x;   // 131072 threads (512 blocks)
  int idx32 = g*2;
  int e = idx32 & 7;
  int q = idx32 >> 3;
  int p = q & 31; q >>= 5;
  int grp = q & 31; q >>= 5;
  int h = q & 15; int b = q >> 4;
  int off32 = (grp*32 + p)*4 + (e>>1);
  uint* st32 = (uint*)(wsb + OFF_ST);
  const float* cdc = (const float*)(wsb + OFF_CDC);
  float S0 = 0.f, S1 = 0.f;
  for (int c=0; c<64; ++c){
    int bi = (b*64+c)*16 + h;
    size_t idx = (size_t)bi*4096 + off32;
    uint v = st32[idx];
    float v0 = bf2f((ushort)(v & 0xFFFFu));
    float v1 = bf2f((ushort)(v >> 16));
    st32[idx] = (uint)f2bf(S0) | ((uint)f2bf(S1) << 16);
    float cd = cdc[bi];
    S0 = fmaf(S0, cd, v0);
    S1 = fmaf(S1, cd, v1);
  }
}

// -------- K4y: y = attn@x + exp2(cum)*C@prev + D*x -> Y bf16 (LDS-staged) -------
__global__ __launch_bounds__(256) void k4y_out(const float* __restrict__ Dp,
                                               char* __restrict__ wsb){
  int bc, h; swz2048(blockIdx.x, bc, h);
  int bi = bc*16 + h;
  __shared__ float sCum[128], sDt[128], sE[128];
  __shared__ __align__(16) char sPrev[16384];   // [grp32][p32][e8] bf16, linear
  __shared__ __align__(16) char sXT[8192];      // [grp16][p32][e8] bf16, linear
  const ushort* cbt = (const ushort*)(wsb + OFF_CBT) + (size_t)bc*16384;
  const char* xtg   = (const char*)(wsb + OFF_XT) + (size_t)bi*8192;
  const char* prevg = (const char*)(wsb + OFF_ST) + (size_t)bi*16384;
  const ushort* bcm = (const ushort*)(wsb + OFF_BCM);
  const float* cum  = (const float*)(wsb + OFF_CUM) + (size_t)bi*128;
  const float* dtp  = (const float*)(wsb + OFF_DT);
  ushort* Yb = (ushort*)(wsb + OFF_Y);
  size_t rb = (size_t)bc*128;
  int tid = threadIdx.x;
  #pragma unroll
  for (int i=0;i<4;++i)
    *(uint4*)(sPrev + i*4096 + tid*16) = *(const uint4*)(prevg + (size_t)i*4096 + tid*16);
  #pragma unroll
  for (int i=0;i<2;++i)
    *(uint4*)(sXT + i*4096 + tid*16) = *(const uint4*)(xtg + (size_t)i*4096 + tid*16);
  if (tid < 128){
    float cv = cum[tid];
    sCum[tid] = cv;
    sDt[tid]  = dtp[(rb+tid)*16 + h];
    sE[tid]   = exp2f(cv);
  }
  __syncthreads();
  int lane = tid&63, wid = tid>>6, l15 = lane&15, l4 = lane>>4;
  int t0 = wid*32 + l15, t1 = t0 + 16;
  float ct0 = sCum[t0], ct1 = sCum[t1];
  // ---- y_intra: A = CBmask*decay*dt in-register; triangle-trimmed ks loop ----
  f32x4 acc[2][2] = {};
  #pragma unroll
  for (int ks = 0; ks < 4; ++ks){
    if (ks <= wid){
      int grp = ks*4 + l4;
      int s0 = grp*8;
      short8 ra0 = *(const short8*)(cbt + (size_t)(grp*128 + t0)*8);
      short8 ra1 = *(const short8*)(cbt + (size_t)(grp*128 + t1)*8);
      short8 a0, a1;
      #pragma unroll
      for (int j=0;j<8;++j){
        int s = s0 + j;
        float cs = sCum[s], ds = sDt[s];
        float e0 = exp2f(fminf(ct0 - cs, 0.f)) * ds;   // clamp mandatory: 0*inf=NaN
        float e1 = exp2f(fminf(ct1 - cs, 0.f)) * ds;
        a0[j] = (short)f2bf(bf2f((ushort)ra0[j]) * e0);  // CBT pre-masked
        a1[j] = (short)f2bf(bf2f((ushort)ra1[j]) * e1);
      }
      short8 b0 = *(const short8*)(sXT + (grp*32 + l15)*16);
      short8 b1 = *(const short8*)(sXT + (grp*32 + 16 + l15)*16);
      acc[0][0] = MFMA16(a0,b0,acc[0][0]);
      acc[0][1] = MFMA16(a0,b1,acc[0][1]);
      acc[1][0] = MFMA16(a1,b0,acc[1][0]);
      acc[1][1] = MFMA16(a1,b1,acc[1][1]);
    }
  }
  // ---- y_inter = C @ prev^T : K=n(256), prev from LDS ----
  f32x4 acc2[2][2] = {};
  #pragma unroll
  for (int ks = 0; ks < 8; ++ks){
    int koff = ks*32 + l4*8;
    int grp = ks*4 + l4;
    short8 a0 = *(const short8*)(bcm + (rb+t0)*512 + 256 + koff);
    short8 a1 = *(const short8*)(bcm + (rb+t1)*512 + 256 + koff);
    short8 b0 = *(const short8*)(sPrev + (grp*32 + l15)*16);
    short8 b1 = *(const short8*)(sPrev + (grp*32 + 16 + l15)*16);
    acc2[0][0] = MFMA16(a0,b0,acc2[0][0]);
    acc2[0][1] = MFMA16(a0,b1,acc2[0][1]);
    acc2[1][0] = MFMA16(a1,b0,acc2[1][0]);
    acc2[1][1] = MFMA16(a1,b1,acc2[1][1]);
  }
  float Dh = Dp[h];
  #pragma unroll
  for (int mt=0; mt<2; ++mt){
    int tb = wid*32 + mt*16 + l4*4;
    int tg = tb>>3, e0i = tb&7;
    #pragma unroll
    for (int nt=0; nt<2; ++nt){
      int p = nt*16 + l15;
      ushort xv[4];
      *(uint2*)xv = *(const uint2*)(sXT + ((tg*32 + p)*8 + e0i)*2);
      #pragma unroll
      for (int r=0; r<4; ++r){
        int t = tb + r;
        float yv = acc[mt][nt][r] + sE[t]*acc2[mt][nt][r] + Dh*bf2f(xv[r]);
        Yb[(rb+t)*512 + h*32 + p] = f2bf(yv);
      }
    }
  }
}

// ---------------- K7: gate(silu(z)) -> RMS -> out_proj (MFMA) -------------------
__global__ __launch_bounds__(256) void k7_final(const float* __restrict__ x,
                                                char* __restrict__ wsb,
                                                float* __restrict__ out){
  int r0 = blockIdx.x*32;                  // 512 blocks
  __shared__ __align__(16) char sG[32768]; // G[32][512] bf16 rows 1024B, swizzled
  __shared__ float sScale[32];
  const ushort* Yb = (const ushort*)(wsb + OFF_Y);
  const float* M  = (const float*)(wsb + OFF_M);
  const float* Cb = (const float*)(wsb + OFF_CB_B);
  const ushort* WT = (const ushort*)(wsb + OFF_WT);
  int tid = threadIdx.x;
  int r = tid>>3, li = tid&7;
  int row = r0 + r; int b = row>>13, l = row & 8191;
  int hh, wv;
  if (l < 4096){ hh = l>>6; wv = l&63; }
  else { int l2 = l-4096; hh = 63-(l2>>6); wv = 63-(l2&63); }
  const float* xb = x + (size_t)b*12288;
  float x0 = xb[hh*64+wv], x1 = xb[4096+hh*64+wv], x2 = xb[8192+hh*64+wv];
  float sq = 0.f;
  #pragma unroll
  for (int k = 0; k < 8; ++k){
    int i0 = li*64 + k*8;
    short8 yv = *(const short8*)(Yb + (size_t)row*512 + i0);
    ushort g8[8];
    #pragma unroll
    for (int j=0;j<8;++j){
      int i = i0 + j;
      float z = Cb[i];
      z = fmaf(x0, M[i], z);
      z = fmaf(x1, M[DPROJ+i], z);
      z = fmaf(x2, M[2*DPROJ+i], z);
      float g = bf2f((ushort)yv[j]) * z * sigm(z);
      sq = fmaf(g, g, sq);
      g8[j] = f2bf(g);
    }
    *(uint4*)(sG + ((r*1024 + i0*2) ^ ((r&7)<<4))) = *(uint4*)g8;
  }
  sq += __shfl_xor(sq, 1, 64);
  sq += __shfl_xor(sq, 2, 64);
  sq += __shfl_xor(sq, 4, 64);
  if (li == 0) sScale[r] = rsqrtf(sq*(1.f/512.f) + 1e-5f);
  __syncthreads();
  int lane = tid&63, wid = tid>>6, l15 = lane&15, l4 = lane>>4;
  f32x4 acc[2][2] = {};
  #pragma unroll
  for (int ks = 0; ks < 16; ++ks){
    int kb = ks*64 + l4*16;
    int rr0 = l15, rr1 = 16+l15;
    short8 a0 = *(const short8*)(sG + ((rr0*1024 + kb) ^ ((rr0&7)<<4)));
    short8 a1 = *(const short8*)(sG + ((rr1*1024 + kb) ^ ((rr1&7)<<4)));
    int koff = ks*32 + l4*8;
    short8 b0 = *(const short8*)(WT + (size_t)(wid*32 + l15)*512 + koff);
    short8 b1 = *(const short8*)(WT + (size_t)(wid*32 + 16 + l15)*512 + koff);
    acc[0][0] = MFMA16(a0,b0,acc[0][0]);
    acc[0][1] = MFMA16(a0,b1,acc[0][1]);
    acc[1][0] = MFMA16(a1,b0,acc[1][0]);
    acc[1][1] = MFMA16(a1,b1,acc[1][1]);
  }
  #pragma unroll
  for (int mt=0; mt<2; ++mt)
  #pragma unroll
  for (int nt=0; nt<2; ++nt)
  #pragma unroll
  for (int r4=0; r4<4; ++r4){
    int rr = mt*16 + l4*4 + r4;
    int d = wid*32 + nt*16 + l15;
    out[(size_t)(r0+rr)*128 + d] = acc[mt][nt][r4] * sScale[rr];
  }
}

extern "C" void kernel_launch(void* const* d_in, const int* in_sizes, int n_in,
                              void* d_out, int out_size, void* d_ws, size_t ws_size,
                              hipStream_t stream) {
  const float* x         = (const float*)d_in[0];
  const float* fc0_w     = (const float*)d_in[1];
  const float* fc0_b     = (const float*)d_in[2];
  const float* in_proj_w = (const float*)d_in[3];
  const float* conv_w    = (const float*)d_in[4];
  const float* conv_b    = (const float*)d_in[5];
  const float* dt_bias   = (const float*)d_in[6];
  const float* A_log     = (const float*)d_in[7];
  const float* Dp        = (const float*)d_in[8];
  const float* norm_w    = (const float*)d_in[9];
  const float* out_proj_w= (const float*)d_in[10];
  char* wsb  = (char*)d_ws;
  float* out = (float*)d_out;

  k0m_prep<<<dim3(128),  dim3(256), 0, stream>>>(fc0_w, fc0_b, in_proj_w, norm_w, out_proj_w, wsb);
  k12_projconv<<<dim3(1024), dim3(256), 0, stream>>>(x, conv_w, conv_b, wsb);
  k4m    <<<dim3(2560),  dim3(256), 0, stream>>>(x, dt_bias, A_log, wsb);
  k5_scan<<<dim3(512),   dim3(256), 0, stream>>>(wsb);
  k4y_out<<<dim3(2048),  dim3(256), 0, stream>>>(Dp, wsb);
  k7_final<<<dim3(512),  dim3(256), 0, stream>>>(x, wsb, out);
}

// Round 12
// 137.727 us; speedup vs baseline: 2.7055x; 1.0051x over previous
//
#include <hip/hip_runtime.h>
#include <hip/hip_bf16.h>

typedef short short8 __attribute__((ext_vector_type(8)));
typedef float f32x4 __attribute__((ext_vector_type(4)));
typedef unsigned short ushort;
typedef unsigned int uint;

#define MFMA16(a,b,c) __builtin_amdgcn_mfma_f32_16x16x32_bf16(a,b,c,0,0,0)
#define DPROJ 1552
#define LOG2E 1.44269504f

// ---- workspace byte offsets ----
constexpr size_t OFF_M    = 0;                         // 3*1552 f32
constexpr size_t OFF_CB_B = 0x5000;                    // 1552 f32
constexpr size_t OFF_WT   = 0x8000;                    // 128*512 bf16
constexpr size_t OFF_XT   = 0x30000;                   // [bc128][h16][grp16][p32][e8] u16 = 16 MB
constexpr size_t OFF_DT   = OFF_XT  + 16777216ull;     // 16384*16 f32
constexpr size_t OFF_BCM  = OFF_DT  + 1048576ull;      // [row][512] u16 (B|C)
constexpr size_t OFF_CUM  = OFF_BCM + 16777216ull;     // 2048*128 f32 (log2 units)
constexpr size_t OFF_CDC  = OFF_CUM + 1048576ull;      // 2048 f32
constexpr size_t OFF_CBT  = OFF_CDC + 8192ull;         // [bc][grp16][t128][e8] u16, PRE-MASKED
constexpr size_t OFF_BT   = OFF_CBT + 4194304ull;      // [bc][grp16][n256][e8] u16 = 8 MB
constexpr size_t OFF_ST   = OFF_BT  + 8388608ull;      // [bi][grp32][p32][e8] u16 = 32 MB
constexpr size_t OFF_Y    = OFF_ST  + 33554432ull;     // 16384*512 bf16

__device__ __forceinline__ float sigm(float x){ return 1.0f/(1.0f + __expf(-x)); }
// HW bf16 convert (RTNE) — compiler fuses pairs into v_cvt_pk_bf16_f32
__device__ __forceinline__ ushort f2bf(float f){
  union { __hip_bfloat16 h; ushort u; } c;
  c.h = __float2bfloat16(f);
  return c.u;
}
__device__ __forceinline__ float bf2f(ushort h){
  union { uint u; float f; } c; c.u = ((uint)h)<<16;
  return c.f;
}
// XCD swizzle for 2048-block grids: all 16 heads of one (b,c) on one XCD
__device__ __forceinline__ void swz2048(int p, int& bc, int& h){
  int xcd = p & 7, slot = p >> 3;
  bc = xcd*16 + (slot >> 4);
  h  = slot & 15;
}

// ------- K0m: fuse fc0 into in_proj + WoutT'[d][i] = norm_w[i]*Wout[i][d] -------
__global__ __launch_bounds__(256) void k0m_prep(const float* __restrict__ fc0_w,
                                                const float* __restrict__ fc0_b,
                                                const float* __restrict__ W,
                                                const float* __restrict__ norm_w,
                                                const float* __restrict__ Wout,
                                                char* __restrict__ wsb){
  int d = blockIdx.x;                     // 128 blocks
  ushort* WT = (ushort*)(wsb + OFF_WT);
  for (int i = threadIdx.x; i < 512; i += 256)
    WT[(size_t)d*512 + i] = f2bf(norm_w[i]*Wout[(size_t)i*128 + d]);
  if (d < 7){
    int j = d*256 + threadIdx.x;
    if (j >= DPROJ) return;
    float* Mo = (float*)(wsb + OFF_M);
    float* Co = (float*)(wsb + OFF_CB_B);
    float m0=0.f,m1=0.f,m2=0.f,cc=0.f;
    for (int dd=0; dd<128; ++dd){
      float w = W[(size_t)dd*DPROJ + j];
      m0 = fmaf(fc0_w[dd],     w, m0);
      m1 = fmaf(fc0_w[128+dd], w, m1);
      m2 = fmaf(fc0_w[256+dd], w, m2);
      cc = fmaf(fc0_b[dd],     w, cc);
    }
    Mo[j] = m0; Mo[DPROJ + j] = m1; Mo[2*DPROJ + j] = m2;
    Co[j] = cc;
  }
}

// ------ K12: fused proj+causal conv(4)+silu -> xT tiled / BC row / BT tiled -----
__device__ __forceinline__ void proj8(int li, const float* __restrict__ xb,
                                      const float* m0, const float* m1, const float* m2,
                                      const float* c8, float* dst){
  if (li < 0){
    #pragma unroll
    for (int j=0;j<8;++j) dst[j] = 0.f;
    return;
  }
  int hh, wv;
  if (li < 4096){ hh = li>>6; wv = li&63; }
  else { int l2 = li-4096; hh = 63-(l2>>6); wv = 63-(l2&63); }
  float x0 = xb[hh*64+wv], x1 = xb[4096+hh*64+wv], x2 = xb[8192+hh*64+wv];
  #pragma unroll
  for (int j=0;j<8;++j)
    dst[j] = fmaf(x2, m2[j], fmaf(x1, m1[j], fmaf(x0, m0[j], c8[j])));
}

__device__ __forceinline__ void conv8(const float* cb8, const float* cw0, const float* cw1,
                                      const float* cw2, const float* cw3,
                                      const float* wA, const float* wB,
                                      const float* wC, const float* wD, ushort* o){
  #pragma unroll
  for (int j=0;j<8;++j){
    float a = cb8[j];
    a = fmaf(wA[j], cw0[j], a);
    a = fmaf(wB[j], cw1[j], a);
    a = fmaf(wC[j], cw2[j], a);
    a = fmaf(wD[j], cw3[j], a);
    o[j] = f2bf(a * sigm(a));
  }
}

__global__ __launch_bounds__(256) void k12_projconv(const float* __restrict__ x,
                                                    const float* __restrict__ conv_w,
                                                    const float* __restrict__ conv_b,
                                                    char* __restrict__ wsb){
  int tid = threadIdx.x;
  int cg = tid & 127, rl = tid >> 7;
  int row0 = blockIdx.x*16 + rl*8;        // 1024 blocks, 16 rows each
  int b = row0 >> 13, l0 = row0 & 8191;
  const float* M  = (const float*)(wsb + OFF_M);
  const float* Cc = (const float*)(wsb + OFF_CB_B);
  const float* xb = x + (size_t)b*12288;
  int ch0 = cg*8, j0 = 512 + ch0;
  float m0[8],m1[8],m2[8],c8[8],cw0[8],cw1[8],cw2[8],cw3[8],cb8[8];
  #pragma unroll
  for (int j=0;j<8;++j){
    m0[j]=M[j0+j]; m1[j]=M[DPROJ+j0+j]; m2[j]=M[2*DPROJ+j0+j]; c8[j]=Cc[j0+j];
    cw0[j]=conv_w[(ch0+j)*4+0]; cw1[j]=conv_w[(ch0+j)*4+1];
    cw2[j]=conv_w[(ch0+j)*4+2]; cw3[j]=conv_w[(ch0+j)*4+3];
    cb8[j]=conv_b[ch0+j];
  }
  bool is_xs = (ch0 < 512);
  bool is_b  = (ch0 >= 512) && (ch0 < 768);
  bool pack  = is_xs || is_b;
  ushort* bcmp = (ushort*)(wsb + OFF_BCM);
  int chb = ch0 - 512;
  uint colw[8][4];        // [ch j][row-pair] packed bf16x2, static idx only
  ushort oprev[8];
  float w0[8],w1[8],w2[8],w3[8];
  ushort o[8];
  proj8(l0-3, xb, m0,m1,m2,c8, w1);
  proj8(l0-2, xb, m0,m1,m2,c8, w2);
  proj8(l0-1, xb, m0,m1,m2,c8, w3);

#define ROW_EVEN(R, WN, WA, WB, WC)                                          \
  proj8(l0+R, xb, m0,m1,m2,c8, WN);                                          \
  conv8(cb8,cw0,cw1,cw2,cw3, WA,WB,WC,WN, o);                                \
  if (pack){ _Pragma("unroll")                                               \
    for (int j=0;j<8;++j) oprev[j] = o[j]; }                                 \
  if (!is_xs) *(uint4*)(bcmp + (size_t)(row0+R)*512 + chb) = *(uint4*)o;
#define ROW_ODD(R, WN, WA, WB, WC)                                           \
  proj8(l0+R, xb, m0,m1,m2,c8, WN);                                          \
  conv8(cb8,cw0,cw1,cw2,cw3, WA,WB,WC,WN, o);                                \
  if (pack){ _Pragma("unroll")                                               \
    for (int j=0;j<8;++j) colw[j][(R)>>1] = (uint)oprev[j] | ((uint)o[j]<<16); } \
  if (!is_xs) *(uint4*)(bcmp + (size_t)(row0+R)*512 + chb) = *(uint4*)o;

  ROW_EVEN(0, w0, w1,w2,w3)
  ROW_ODD (1, w1, w2,w3,w0)
  ROW_EVEN(2, w2, w3,w0,w1)
  ROW_ODD (3, w3, w0,w1,w2)
  ROW_EVEN(4, w0, w1,w2,w3)
  ROW_ODD (5, w1, w2,w3,w0)
  ROW_EVEN(6, w2, w3,w0,w1)
  ROW_ODD (7, w3, w0,w1,w2)
#undef ROW_EVEN
#undef ROW_ODD

  int bc = row0>>7, grp = (row0&127)>>3;
  if (is_xs){
    int h = ch0>>5, p0 = ch0&31;
    ushort* dst = (ushort*)(wsb+OFF_XT) + (((size_t)(bc*16+h)*16 + grp)*32)*8;
    #pragma unroll
    for (int j=0;j<8;++j){
      uint4 v; v.x = colw[j][0]; v.y = colw[j][1]; v.z = colw[j][2]; v.w = colw[j][3];
      *(uint4*)(dst + (size_t)(p0+j)*8) = v;
    }
  } else if (is_b){
    // BT tiled: [bc][grp16][n256][e8]
    ushort* btb = (ushort*)(wsb+OFF_BT) + (size_t)bc*32768;
    #pragma unroll
    for (int j=0;j<8;++j){
      uint4 v; v.x = colw[j][0]; v.y = colw[j][1]; v.z = colw[j][2]; v.w = colw[j][3];
      *(uint4*)(btb + (size_t)(grp*256 + chb + j)*8) = v;
    }
  }
}

// ---- K4m: merged {k4a: CB MFMA, de-LDS'd, blocks 0..511} /
//                  {k4sc: dt-proj + wave-scan cumsum + states, blocks 512..2559} --
__global__ __launch_bounds__(256) void k4m(const float* __restrict__ x,
                                           const float* __restrict__ dt_bias,
                                           const float* __restrict__ A_log,
                                           char* __restrict__ wsb){
  __shared__ float sCS[128];
  __shared__ float sW[128];
  int tid = threadIdx.x;
  int lane = tid&63, wid = tid>>6, l15 = lane&15, l4 = lane>>4;

  if (blockIdx.x < 512){
    // ============ k4a path: CB = C·B^T, frags direct from global, no LDS ========
    int bi4 = blockIdx.x;                 // (b*64+c)*4 + squad
    int sq = bi4 & 3; int bc = bi4 >> 2;
    const ushort* bcm = (const ushort*)(wsb + OFF_BCM);
    ushort* cbtT = (ushort*)(wsb + OFF_CBT) + (size_t)bc*16384;
    size_t rb = (size_t)bc*128;
    int s_base = sq*32;
    f32x4 acc[2][2] = {};
    if (wid >= sq){                       // triangle trim
      int t0 = wid*32 + l15, t1 = t0 + 16;
      #pragma unroll
      for (int kk = 0; kk < 8; ++kk){     // K = n = 256 in 8 steps of 32
        int ko = kk*32 + l4*8;
        short8 a0 = *(const short8*)(bcm + (rb+t0)*512 + 256 + ko);
        short8 a1 = *(const short8*)(bcm + (rb+t1)*512 + 256 + ko);
        short8 b0 = *(const short8*)(bcm + (rb + s_base + l15)*512 + ko);
        short8 b1 = *(const short8*)(bcm + (rb + s_base + 16 + l15)*512 + ko);
        acc[0][0] = MFMA16(a0,b0,acc[0][0]);
        acc[0][1] = MFMA16(a0,b1,acc[0][1]);
        acc[1][0] = MFMA16(a1,b0,acc[1][0]);
        acc[1][1] = MFMA16(a1,b1,acc[1][1]);
      }
    }
    #pragma unroll
    for (int mt=0; mt<2; ++mt)
    #pragma unroll
    for (int st=0; st<2; ++st)
    #pragma unroll
    for (int r=0; r<4; ++r){
      int t = wid*32 + mt*16 + l4*4 + r;
      int s = s_base + st*16 + l15;
      float v = (t >= s) ? acc[mt][st][r] : 0.f;   // pre-mask upper triangle
      cbtT[(size_t)((s>>3)*128 + t)*8 + (s&7)] = f2bf(v);
    }
    return;
  }

  // ============ k4sc path ============
  int bc, h; swz2048(blockIdx.x - 512, bc, h);
  int bi = bc*16 + h;
  const ushort* xt  = (const ushort*)(wsb + OFF_XT) + (size_t)bi*4096;
  const ushort* btb = (const ushort*)(wsb + OFF_BT) + (size_t)bc*32768;
  ushort* st = (ushort*)(wsb + OFF_ST) + (size_t)bi*8192;
  float dtv = 0.f, v = 0.f;
  if (tid < 128){
    int r = bc*128 + tid;
    int b = r >> 13, l = r & 8191;
    int hp, wv;
    if (l < 4096){ hp = l>>6; wv = l&63; }
    else { int l2 = l-4096; hp = 63-(l2>>6); wv = 63-(l2&63); }
    const float* xb = x + (size_t)b*12288;
    float x0 = xb[hp*64+wv], x1 = xb[4096+hp*64+wv], x2 = xb[8192+hp*64+wv];
    const float* M  = (const float*)(wsb + OFF_M);
    const float* Cc = (const float*)(wsb + OFF_CB_B);
    int j = 1536 + h;
    float vv = Cc[j];
    vv = fmaf(x0, M[j], vv);
    vv = fmaf(x1, M[DPROJ+j], vv);
    vv = fmaf(x2, M[2*DPROJ+j], vv);
    float tt = vv + dt_bias[h];
    dtv = (tt > 20.f) ? tt : log1pf(__expf(tt));
    ((float*)(wsb+OFF_DT))[(size_t)r*16 + h] = dtv;
    float A2 = -__expf(A_log[h]) * LOG2E;
    v = dtv * A2;
  }
  // in-wave inclusive scan (waves 0,1 carry t=0..127)
  #pragma unroll
  for (int off=1; off<64; off<<=1){
    float u = __shfl_up(v, off, 64);
    if (lane >= off) v += u;
  }
  if (tid < 128) sCS[tid] = v;
  __syncthreads();
  if (tid >= 64 && tid < 128) sCS[tid] = v + sCS[63];
  __syncthreads();
  if (tid < 128){
    float cv = sCS[tid];
    ((float*)(wsb + OFF_CUM))[(size_t)bi*128 + tid] = cv;
    if (tid == 127) ((float*)(wsb + OFF_CDC))[bi] = exp2f(cv);
    sW[tid] = exp2f(sCS[127] - cv) * dtv;
  }
  __syncthreads();
  f32x4 acc2[2][4] = {};
  #pragma unroll
  for (int ks = 0; ks < 4; ++ks){
    int grp = ks*4 + l4;
    const float* wp = sW + grp*8;
    short8 ra0 = *(const short8*)(xt + (size_t)(grp*32 + l15)*8);
    short8 ra1 = *(const short8*)(xt + (size_t)(grp*32 + 16 + l15)*8);
    short8 a0, a1;
    #pragma unroll
    for (int j=0;j<8;++j){
      a0[j] = (short)f2bf(bf2f((ushort)ra0[j]) * wp[j]);
      a1[j] = (short)f2bf(bf2f((ushort)ra1[j]) * wp[j]);
    }
    #pragma unroll
    for (int ntl = 0; ntl < 4; ++ntl){
      int n = wid*64 + ntl*16 + l15;
      short8 b = *(const short8*)(btb + (size_t)(grp*256 + n)*8);
      acc2[0][ntl] = MFMA16(a0,b,acc2[0][ntl]);
      acc2[1][ntl] = MFMA16(a1,b,acc2[1][ntl]);
    }
  }
  #pragma unroll
  for (int mt=0; mt<2; ++mt)
  #pragma unroll
  for (int ntl=0; ntl<4; ++ntl)
  #pragma unroll
  for (int r=0; r<4; ++r){
    int p = mt*16 + l4*4 + r;
    int n = wid*64 + ntl*16 + l15;
    st[(size_t)((n>>3)*32 + p)*8 + (n&7)] = f2bf(acc2[mt][ntl][r]);
  }
}

// ---------------- K5: sequential chunk scan, pack-2 (uint per thread) -----------
__global__ __launch_bounds__(256) void k5_scan(char* __restrict__ wsb){
  int g = blockIdx.x*256 + threadIdx.x;   // 131072 threads (512 blocks)
  int idx32 = g*2;
  int e = idx32 & 7;
  int q = idx32 >> 3;
  int p = q & 31; q >>= 5;
  int grp = q & 31; q >>= 5;
  int h = q & 15; int b = q >> 4;
  int off32 = (grp*32 + p)*4 + (e>>1);
  uint* st32 = (uint*)(wsb + OFF_ST);
  const float* cdc = (const float*)(wsb + OFF_CDC);
  float S0 = 0.f, S1 = 0.f;
  for (int c=0; c<64; ++c){
    int bi = (b*64+c)*16 + h;
    size_t idx = (size_t)bi*4096 + off32;
    uint v = st32[idx];
    float v0 = bf2f((ushort)(v & 0xFFFFu));
    float v1 = bf2f((ushort)(v >> 16));
    st32[idx] = (uint)f2bf(S0) | ((uint)f2bf(S1) << 16);
    float cd = cdc[bi];
    S0 = fmaf(S0, cd, v0);
    S1 = fmaf(S1, cd, v1);
  }
}

// -------- K4y: y = attn@x + exp2(cum)*C@prev + D*x -> Y bf16 (LDS-staged) -------
__global__ __launch_bounds__(256) void k4y_out(const float* __restrict__ Dp,
                                               char* __restrict__ wsb){
  int bc, h; swz2048(blockIdx.x, bc, h);
  int bi = bc*16 + h;
  __shared__ float sCum[128], sDt[128], sE[128];
  __shared__ __align__(16) char sPrev[16384];   // [grp32][p32][e8] bf16, linear
  __shared__ __align__(16) char sXT[8192];      // [grp16][p32][e8] bf16, linear
  const ushort* cbt = (const ushort*)(wsb + OFF_CBT) + (size_t)bc*16384;
  const char* xtg   = (const char*)(wsb + OFF_XT) + (size_t)bi*8192;
  const char* prevg = (const char*)(wsb + OFF_ST) + (size_t)bi*16384;
  const ushort* bcm = (const ushort*)(wsb + OFF_BCM);
  const float* cum  = (const float*)(wsb + OFF_CUM) + (size_t)bi*128;
  const float* dtp  = (const float*)(wsb + OFF_DT);
  ushort* Yb = (ushort*)(wsb + OFF_Y);
  size_t rb = (size_t)bc*128;
  int tid = threadIdx.x;
  #pragma unroll
  for (int i=0;i<4;++i)
    *(uint4*)(sPrev + i*4096 + tid*16) = *(const uint4*)(prevg + (size_t)i*4096 + tid*16);
  #pragma unroll
  for (int i=0;i<2;++i)
    *(uint4*)(sXT + i*4096 + tid*16) = *(const uint4*)(xtg + (size_t)i*4096 + tid*16);
  if (tid < 128){
    float cv = cum[tid];
    sCum[tid] = cv;
    sDt[tid]  = dtp[(rb+tid)*16 + h];
    sE[tid]   = exp2f(cv);
  }
  __syncthreads();
  int lane = tid&63, wid = tid>>6, l15 = lane&15, l4 = lane>>4;
  int t0 = wid*32 + l15, t1 = t0 + 16;
  float ct0 = sCum[t0], ct1 = sCum[t1];
  // ---- y_intra: A = CBmask*decay*dt in-register; triangle-trimmed ks loop ----
  f32x4 acc[2][2] = {};
  #pragma unroll
  for (int ks = 0; ks < 4; ++ks){
    if (ks <= wid){
      int grp = ks*4 + l4;
      int s0 = grp*8;
      short8 ra0 = *(const short8*)(cbt + (size_t)(grp*128 + t0)*8);
      short8 ra1 = *(const short8*)(cbt + (size_t)(grp*128 + t1)*8);
      short8 a0, a1;
      #pragma unroll
      for (int j=0;j<8;++j){
        int s = s0 + j;
        float cs = sCum[s], ds = sDt[s];
        float e0 = exp2f(fminf(ct0 - cs, 0.f)) * ds;   // clamp mandatory: 0*inf=NaN
        float e1 = exp2f(fminf(ct1 - cs, 0.f)) * ds;
        a0[j] = (short)f2bf(bf2f((ushort)ra0[j]) * e0);  // CBT pre-masked
        a1[j] = (short)f2bf(bf2f((ushort)ra1[j]) * e1);
      }
      short8 b0 = *(const short8*)(sXT + (grp*32 + l15)*16);
      short8 b1 = *(const short8*)(sXT + (grp*32 + 16 + l15)*16);
      acc[0][0] = MFMA16(a0,b0,acc[0][0]);
      acc[0][1] = MFMA16(a0,b1,acc[0][1]);
      acc[1][0] = MFMA16(a1,b0,acc[1][0]);
      acc[1][1] = MFMA16(a1,b1,acc[1][1]);
    }
  }
  // ---- y_inter = C @ prev^T : K=n(256), prev from LDS ----
  f32x4 acc2[2][2] = {};
  #pragma unroll
  for (int ks = 0; ks < 8; ++ks){
    int koff = ks*32 + l4*8;
    int grp = ks*4 + l4;
    short8 a0 = *(const short8*)(bcm + (rb+t0)*512 + 256 + koff);
    short8 a1 = *(const short8*)(bcm + (rb+t1)*512 + 256 + koff);
    short8 b0 = *(const short8*)(sPrev + (grp*32 + l15)*16);
    short8 b1 = *(const short8*)(sPrev + (grp*32 + 16 + l15)*16);
    acc2[0][0] = MFMA16(a0,b0,acc2[0][0]);
    acc2[0][1] = MFMA16(a0,b1,acc2[0][1]);
    acc2[1][0] = MFMA16(a1,b0,acc2[1][0]);
    acc2[1][1] = MFMA16(a1,b1,acc2[1][1]);
  }
  float Dh = Dp[h];
  #pragma unroll
  for (int mt=0; mt<2; ++mt){
    int tb = wid*32 + mt*16 + l4*4;
    int tg = tb>>3, e0i = tb&7;
    #pragma unroll
    for (int nt=0; nt<2; ++nt){
      int p = nt*16 + l15;
      ushort xv[4];
      *(uint2*)xv = *(const uint2*)(sXT + ((tg*32 + p)*8 + e0i)*2);
      #pragma unroll
      for (int r=0; r<4; ++r){
        int t = tb + r;
        float yv = acc[mt][nt][r] + sE[t]*acc2[mt][nt][r] + Dh*bf2f(xv[r]);
        Yb[(rb+t)*512 + h*32 + p] = f2bf(yv);
      }
    }
  }
}

// ---------------- K7: gate(silu(z)) -> RMS -> out_proj (MFMA) -------------------
__global__ __launch_bounds__(256) void k7_final(const float* __restrict__ x,
                                                char* __restrict__ wsb,
                                                float* __restrict__ out){
  int r0 = blockIdx.x*32;                  // 512 blocks
  __shared__ __align__(16) char sG[32768]; // G[32][512] bf16 rows 1024B, swizzled
  __shared__ float sScale[32];
  const ushort* Yb = (const ushort*)(wsb + OFF_Y);
  const float* M  = (const float*)(wsb + OFF_M);
  const float* Cb = (const float*)(wsb + OFF_CB_B);
  const ushort* WT = (const ushort*)(wsb + OFF_WT);
  int tid = threadIdx.x;
  int r = tid>>3, li = tid&7;
  int row = r0 + r; int b = row>>13, l = row & 8191;
  int hh, wv;
  if (l < 4096){ hh = l>>6; wv = l&63; }
  else { int l2 = l-4096; hh = 63-(l2>>6); wv = 63-(l2&63); }
  const float* xb = x + (size_t)b*12288;
  float x0 = xb[hh*64+wv], x1 = xb[4096+hh*64+wv], x2 = xb[8192+hh*64+wv];
  float sq = 0.f;
  #pragma unroll
  for (int k = 0; k < 8; ++k){
    int i0 = li*64 + k*8;
    short8 yv = *(const short8*)(Yb + (size_t)row*512 + i0);
    ushort g8[8];
    #pragma unroll
    for (int j=0;j<8;++j){
      int i = i0 + j;
      float z = Cb[i];
      z = fmaf(x0, M[i], z);
      z = fmaf(x1, M[DPROJ+i], z);
      z = fmaf(x2, M[2*DPROJ+i], z);
      float g = bf2f((ushort)yv[j]) * z * sigm(z);
      sq = fmaf(g, g, sq);
      g8[j] = f2bf(g);
    }
    *(uint4*)(sG + ((r*1024 + i0*2) ^ ((r&7)<<4))) = *(uint4*)g8;
  }
  sq += __shfl_xor(sq, 1, 64);
  sq += __shfl_xor(sq, 2, 64);
  sq += __shfl_xor(sq, 4, 64);
  if (li == 0) sScale[r] = rsqrtf(sq*(1.f/512.f) + 1e-5f);
  __syncthreads();
  int lane = tid&63, wid = tid>>6, l15 = lane&15, l4 = lane>>4;
  f32x4 acc[2][2] = {};
  #pragma unroll
  for (int ks = 0; ks < 16; ++ks){
    int kb = ks*64 + l4*16;
    int rr0 = l15, rr1 = 16+l15;
    short8 a0 = *(const short8*)(sG + ((rr0*1024 + kb) ^ ((rr0&7)<<4)));
    short8 a1 = *(const short8*)(sG + ((rr1*1024 + kb) ^ ((rr1&7)<<4)));
    int koff = ks*32 + l4*8;
    short8 b0 = *(const short8*)(WT + (size_t)(wid*32 + l15)*512 + koff);
    short8 b1 = *(const short8*)(WT + (size_t)(wid*32 + 16 + l15)*512 + koff);
    acc[0][0] = MFMA16(a0,b0,acc[0][0]);
    acc[0][1] = MFMA16(a0,b1,acc[0][1]);
    acc[1][0] = MFMA16(a1,b0,acc[1][0]);
    acc[1][1] = MFMA16(a1,b1,acc[1][1]);
  }
  #pragma unroll
  for (int mt=0; mt<2; ++mt)
  #pragma unroll
  for (int nt=0; nt<2; ++nt)
  #pragma unroll
  for (int r4=0; r4<4; ++r4){
    int rr = mt*16 + l4*4 + r4;
    int d = wid*32 + nt*16 + l15;
    out[(size_t)(r0+rr)*128 + d] = acc[mt][nt][r4] * sScale[rr];
  }
}

extern "C" void kernel_launch(void* const* d_in, const int* in_sizes, int n_in,
                              void* d_out, int out_size, void* d_ws, size_t ws_size,
                              hipStream_t stream) {
  const float* x         = (const float*)d_in[0];
  const float* fc0_w     = (const float*)d_in[1];
  const float* fc0_b     = (const float*)d_in[2];
  const float* in_proj_w = (const float*)d_in[3];
  const float* conv_w    = (const float*)d_in[4];
  const float* conv_b    = (const float*)d_in[5];
  const float* dt_bias   = (const float*)d_in[6];
  const float* A_log     = (const float*)d_in[7];
  const float* Dp        = (const float*)d_in[8];
  const float* norm_w    = (const float*)d_in[9];
  const float* out_proj_w= (const float*)d_in[10];
  char* wsb  = (char*)d_ws;
  float* out = (float*)d_out;

  k0m_prep<<<dim3(128),  dim3(256), 0, stream>>>(fc0_w, fc0_b, in_proj_w, norm_w, out_proj_w, wsb);
  k12_projconv<<<dim3(1024), dim3(256), 0, stream>>>(x, conv_w, conv_b, wsb);
  k4m    <<<dim3(2560),  dim3(256), 0, stream>>>(x, dt_bias, A_log, wsb);
  k5_scan<<<dim3(512),   dim3(256), 0, stream>>>(wsb);
  k4y_out<<<dim3(2048),  dim3(256), 0, stream>>>(Dp, wsb);
  k7_final<<<dim3(512),  dim3(256), 0, stream>>>(x, wsb, out);
}